// Round 6
// baseline (826.608 us; speedup 1.0000x reference)
//
#include <hip/hip_runtime.h>

#define NT    8192
#define NP    8200
#define NPP   8320          // 65 * 128 = 260 * 32
#define NB    64
#define DV    64
#define NL    4
#define KSB   65            // one 128-t subtile per k_inv block
#define KSV   13            // k-split for v-DFT
#define PI2   6.28318530717958647692f
#define FP_S  1048576.0f    // 2^20 fixed-point scale
#define FP_SI (1.0 / 1048576.0)

typedef _Float16 half8 __attribute__((ext_vector_type(8)));
typedef _Float16 half4 __attribute__((ext_vector_type(4)));
typedef float    f32x4 __attribute__((ext_vector_type(4)));

// ---------------- workspace layout (bytes) ----------------
// xT    : [NB][NPP][DV] f16                      68,157,440
// tabF  : [260][8][64][8] f16                     2,129,920
// tabI  : [4][520][64][8] f16 (alpha folded)      2,129,920
// Wfrag : [NL][2 hilo][2 ks][4 mf][64][8] f16       131,072
// zfrag : [NB][4][4][64][8] f16                   1,048,576
// Xacc  : [NB][DV][128] i64 (fixed-point)         4,194,304
// Vpart : [KSV][NB][128] f16                        212,992
// G     : [128] f32                                     512
static const size_t B_XT   = 0;
static const size_t B_TABF = 68157440ull;
static const size_t B_TABI = B_TABF + 2129920ull;
static const size_t B_WFR  = B_TABI + 2129920ull;
static const size_t B_ZFR  = B_WFR  + 131072ull;
static const size_t B_XA   = B_ZFR  + 1048576ull;
static const size_t B_VP   = B_XA   + 4194304ull;
static const size_t B_G    = B_VP   + 212992ull;

// ---------------- trig tables in MFMA fragment order ----------------
__global__ void k_prep(_Float16* __restrict__ tabF, _Float16* __restrict__ tabI) {
    int idx = blockIdx.x * 256 + threadIdx.x;
    if (idx >= NPP * 64) return;
    int t = idx >> 6, k = idx & 63;
    float c = 0.f, s = 0.f;
    if (t < NP) {
        int m = (int)(((long long)t * (long long)k) % NP);
        float th = (float)m * (PI2 / (float)NP);
        sincosf(th, &s, &c);
    }
    float al = (k == 0) ? (1.f / NP) : (2.f / NP);
    // tabF: B[k-dim=t][col=m]: step=t>>5, cf=m>>4, lane=(m&15)+16*((t>>3)&3), j=t&7
    {
        int gs = t >> 5, lh = (t >> 3) & 3, j = t & 7, cf = k >> 3;
        int m0 = 2 * k, m1 = 2 * k + 1;
        tabF[(((size_t)gs * 8 + cf) * 64 + (m0 & 15) + 16 * lh) * 8 + j] = (_Float16)c;
        tabF[(((size_t)gs * 8 + cf) * 64 + (m1 & 15) + 16 * lh) * 8 + j] = (_Float16)s;
    }
    // tabI: B[k-dim=m][col=t]: ks=m>>5, tf=t>>4, lane=(t&15)+16*((m>>3)&3), j=m&7
    {
        int tf = t >> 4, lt = t & 15;
        int m0 = 2 * k, m1 = 2 * k + 1;
        tabI[(((size_t)(m0 >> 5) * 520 + tf) * 64 + lt + 16 * ((m0 >> 3) & 3)) * 8 + (m0 & 7)] = (_Float16)(al * c);
        tabI[(((size_t)(m1 >> 5) * 520 + tf) * 64 + lt + 16 * ((m1 >> 3) & 3)) * 8 + (m1 & 7)] = (_Float16)(al * s);
    }
}

// ---------------- w_w hi/lo f16 in A-frag order ----------------
__global__ void k_prep_w(const float* __restrict__ ww, _Float16* __restrict__ Wfrag) {
    int idx = blockIdx.x * 256 + threadIdx.x;
    if (idx >= NL * DV * DV) return;
    int l = idx >> 12, cd = idx & 4095, c = cd >> 6, d = cd & 63;
    float wv = ww[((size_t)l * DV + c) * DV + d];     // A[row=d][k=c]
    _Float16 h = (_Float16)wv;
    _Float16 lo = (_Float16)(wv - (float)h);
    int ks = c >> 5, mf = d >> 4;
    int lane = (d & 15) + 16 * ((c >> 3) & 3), j = c & 7;
    Wfrag[((((size_t)l * 2 + 0) * 2 + ks) * 4 + mf) * 512 + (size_t)lane * 8 + j] = h;
    Wfrag[((((size_t)l * 2 + 1) * 2 + ks) * 4 + mf) * 512 + (size_t)lane * 8 + j] = lo;
}

// ---------------- G[m] = DFT(grid) ----------------
__global__ void k_gd(const float* __restrict__ grd, float* __restrict__ G) {
    __shared__ float rb[256];
    int m = blockIdx.x, k = m >> 1, comp = m & 1;
    int tid = threadIdx.x;
    float s = 0.f;
    for (int t = tid; t < NT; t += 256) {
        int mm = (int)(((long long)t * (long long)k) % NP);
        float th = (float)mm * (PI2 / (float)NP);
        float sn, cs; sincosf(th, &sn, &cs);
        s += grd[t] * (comp ? sn : cs);
    }
    rb[tid] = s; __syncthreads();
    for (int h = 128; h > 0; h >>= 1) { if (tid < h) rb[tid] += rb[tid + h]; __syncthreads(); }
    if (tid == 0) G[m] = rb[0];
}

// ---------------- initial projection -> xT[b][t][c] f16 ----------------
__global__ void k_proj(const float* __restrict__ v, const float* __restrict__ grd,
                       const float* __restrict__ pw, const float* __restrict__ pb,
                       _Float16* __restrict__ xT) {
    int b = blockIdx.y;
    int t = blockIdx.x * 128 + (threadIdx.x >> 1);
    int hf = threadIdx.x & 1;
    bool in = (t < NT);
    float vv = in ? v[(size_t)b * NT + t] : 0.f;
    float gg = in ? grd[t] : 0.f;
    _Float16 buf[32];
    #pragma unroll
    for (int q = 0; q < 32; ++q) {
        int c = hf * 32 + q;
        float val = in ? fmaf(vv, pw[c], fmaf(gg, pw[64 + c], pb[c])) : 0.f;
        buf[q] = (_Float16)val;
    }
    #pragma unroll
    for (int q = 0; q < 4; ++q)
        *(half8*)&xT[((size_t)b * NPP + t) * 64 + hf * 32 + q * 8] = *(half8*)&buf[q * 8];
}

// ---------------- partial DFT of v (A rows = batch) ----------------
__launch_bounds__(256)
__global__ void k_fdft_v(const float* __restrict__ v, const _Float16* __restrict__ tabF,
                         _Float16* __restrict__ Vp) {
    int ksb = blockIdx.x;
    int tid = threadIdx.x, w = tid >> 6, lane = tid & 63, g = lane >> 4, r = lane & 15;
    const half8* tFv = (const half8*)tabF;
    f32x4 acc[4][2];
    #pragma unroll
    for (int mf = 0; mf < 4; ++mf)
        #pragma unroll
        for (int nf = 0; nf < 2; ++nf) acc[mf][nf] = (f32x4){0.f, 0.f, 0.f, 0.f};
    for (int s = 0; s < 20; ++s) {
        int gs = ksb * 20 + s;
        int t0 = gs * 32 + g * 8;
        half8 a[4];
        #pragma unroll
        for (int mf = 0; mf < 4; ++mf) {
            int brow = mf * 16 + r;
            half8 hv;
            if (t0 < NT) {
                const float4* pv = (const float4*)&v[(size_t)brow * NT + t0];
                float4 v0 = pv[0], v1 = pv[1];
                hv[0] = (_Float16)v0.x; hv[1] = (_Float16)v0.y; hv[2] = (_Float16)v0.z; hv[3] = (_Float16)v0.w;
                hv[4] = (_Float16)v1.x; hv[5] = (_Float16)v1.y; hv[6] = (_Float16)v1.z; hv[7] = (_Float16)v1.w;
            } else {
                #pragma unroll
                for (int j = 0; j < 8; ++j) hv[j] = (_Float16)0.f;
            }
            a[mf] = hv;
        }
        half8 bb[2];
        #pragma unroll
        for (int nf = 0; nf < 2; ++nf) bb[nf] = tFv[((size_t)gs * 8 + w * 2 + nf) * 64 + lane];
        #pragma unroll
        for (int mf = 0; mf < 4; ++mf)
            #pragma unroll
            for (int nf = 0; nf < 2; ++nf)
                acc[mf][nf] = __builtin_amdgcn_mfma_f32_16x16x32_f16(a[mf], bb[nf], acc[mf][nf], 0, 0, 0);
    }
    #pragma unroll
    for (int mf = 0; mf < 4; ++mf)
        #pragma unroll
        for (int nf = 0; nf < 2; ++nf)
            #pragma unroll
            for (int reg = 0; reg < 4; ++reg) {
                int brow = mf * 16 + g * 4 + reg;
                int m = w * 32 + nf * 16 + r;
                Vp[((size_t)ksb * NB + brow) * 128 + m] = (_Float16)acc[mf][nf][reg];
            }
}

// ---------------- spectral mix layer 0 (rank-2 X build) ----------------
__launch_bounds__(256)
__global__ void k_spec0(const _Float16* __restrict__ Vp, const float* __restrict__ G,
                        const float* __restrict__ pw, const float* __restrict__ pb,
                        const float* __restrict__ fw_l, _Float16* __restrict__ zfr) {
    __shared__ float Xs[64][32];
    __shared__ float Vs[32], Gs[32];
    int b = blockIdx.y, kq = blockIdx.x, tid = threadIdx.x;
    if (tid < 32) {
        int m = kq * 32 + tid;
        float ssum = 0.f;
        #pragma unroll
        for (int ks = 0; ks < KSV; ++ks) ssum += (float)Vp[((size_t)ks * NB + b) * 128 + m];
        Vs[tid] = ssum;
        Gs[tid] = G[m];
    }
    __syncthreads();
    #pragma unroll
    for (int q = 0; q < 8; ++q) {
        int flat = q * 256 + tid;
        int i = flat >> 5, ml = flat & 31;
        float xv = pw[i] * Vs[ml] + pw[64 + i] * Gs[ml];
        if (kq == 0 && ml == 0) xv += pb[i] * (float)NT;
        Xs[i][ml] = xv;
    }
    __syncthreads();
    #pragma unroll
    for (int q = 0; q < 4; ++q) {
        int flat = q * 256 + tid;
        int o = flat >> 4, kl = flat & 15;
        int k = kq * 16 + kl;
        float yr = 0.f, yi = 0.f;
        #pragma unroll 8
        for (int i = 0; i < 64; ++i) {
            float2 xv = *(const float2*)&Xs[i][2 * kl];
            float2 wv = *(const float2*)&fw_l[(((size_t)i * DV + o) * 64 + k) * 2];
            yr = fmaf(xv.x, wv.x, fmaf(xv.y, wv.y, yr));
            yi = fmaf(xv.x, wv.y, fmaf(-xv.y, wv.x, yi));
        }
        int mf = o >> 4, mm = 2 * kl, m1 = mm + 1;
        zfr[((((size_t)b * 4 + kq) * 4 + mf) * 64 + (o & 15) + 16 * (mm >> 3)) * 8 + (mm & 7)] = (_Float16)yr;
        zfr[((((size_t)b * 4 + kq) * 4 + mf) * 64 + (o & 15) + 16 * (m1 >> 3)) * 8 + (m1 & 7)] = (_Float16)(-yi);
    }
}

// ---------------- spectral mix layers 1..3 (read i64 accumulator) ----------------
__launch_bounds__(256)
__global__ void k_spec(const unsigned long long* __restrict__ Xacc, const float* __restrict__ fw_l,
                       _Float16* __restrict__ zfr) {
    __shared__ float Xs[64][32];
    int b = blockIdx.y, kq = blockIdx.x, tid = threadIdx.x;
    #pragma unroll
    for (int q = 0; q < 8; ++q) {
        int flat = q * 256 + tid;
        int i = flat >> 5, ml = flat & 31;
        long long raw = (long long)Xacc[((size_t)b * DV + i) * 128 + kq * 32 + ml];
        Xs[i][ml] = (float)((double)raw * FP_SI);
    }
    __syncthreads();
    #pragma unroll
    for (int q = 0; q < 4; ++q) {
        int flat = q * 256 + tid;
        int o = flat >> 4, kl = flat & 15;
        int k = kq * 16 + kl;
        float yr = 0.f, yi = 0.f;
        #pragma unroll 8
        for (int i = 0; i < 64; ++i) {
            float2 xv = *(const float2*)&Xs[i][2 * kl];
            float2 wv = *(const float2*)&fw_l[(((size_t)i * DV + o) * 64 + k) * 2];
            yr = fmaf(xv.x, wv.x, fmaf(xv.y, wv.y, yr));
            yi = fmaf(xv.x, wv.y, fmaf(-xv.y, wv.x, yi));
        }
        int mf = o >> 4, mm = 2 * kl, m1 = mm + 1;
        zfr[((((size_t)b * 4 + kq) * 4 + mf) * 64 + (o & 15) + 16 * (mm >> 3)) * 8 + (mm & 7)] = (_Float16)yr;
        zfr[((((size_t)b * 4 + kq) * 4 + mf) * 64 + (o & 15) + 16 * (m1 >> 3)) * 8 + (m1 & 7)] = (_Float16)(-yi);
    }
}

// ---------------- fused: inverse DFT + local + bias + relu + fwd DFT (1 subtile/block) ----------------
template <bool LAST>
__launch_bounds__(256)
__global__ void k_inv(const _Float16* __restrict__ zfr, const _Float16* __restrict__ tabI,
                      const _Float16* __restrict__ tabF, const _Float16* __restrict__ Wl,
                      const float* __restrict__ wb_l, const float* __restrict__ qw,
                      const float* __restrict__ qb, _Float16* __restrict__ xT,
                      unsigned long long* __restrict__ Xacc, float* __restrict__ out) {
    __shared__ _Float16 xls[64 * 128];    // [c][t-swizzled] 16 KiB
    __shared__ float red[4][2][64];
    int b = blockIdx.y, ksb = blockIdx.x;
    int tid = threadIdx.x, w = tid >> 6, lane = tid & 63;
    int g = lane >> 4, r = lane & 15;
    int tw = ksb * 128 + w * 32;
    const half8* zfv = (const half8*)zfr;
    const half8* tIv = (const half8*)tabI;
    const half8* tFv = (const half8*)tabF;
    const half8* wfv = (const half8*)Wl;

    // ---- old-x B-frags (direct coalesced global, this wave's own 32-t slice) ----
    half8 xb[2][2];
    #pragma unroll
    for (int ks = 0; ks < 2; ++ks)
        #pragma unroll
        for (int nf = 0; nf < 2; ++nf)
            xb[ks][nf] = *(const half8*)&xT[((size_t)b * NPP + tw + nf * 16 + r) * 64 + ks * 32 + g * 8];

    f32x4 acc[4][2];
    #pragma unroll
    for (int mf = 0; mf < 4; ++mf)
        #pragma unroll
        for (int nf = 0; nf < 2; ++nf) acc[mf][nf] = (f32x4){0.f, 0.f, 0.f, 0.f};

    // ---- spectral: A=z, B=tabI ----
    #pragma unroll
    for (int ks4 = 0; ks4 < 4; ++ks4) {
        half8 az[4], bt[2];
        #pragma unroll
        for (int mf = 0; mf < 4; ++mf)
            az[mf] = zfv[(((size_t)b * 4 + ks4) * 4 + mf) * 64 + lane];
        #pragma unroll
        for (int nf = 0; nf < 2; ++nf)
            bt[nf] = tIv[((size_t)ks4 * 520 + (tw >> 4) + nf) * 64 + lane];
        #pragma unroll
        for (int mf = 0; mf < 4; ++mf)
            #pragma unroll
            for (int nf = 0; nf < 2; ++nf)
                acc[mf][nf] = __builtin_amdgcn_mfma_f32_16x16x32_f16(az[mf], bt[nf], acc[mf][nf], 0, 0, 0);
    }
    // ---- local: (Whi + Wlo) * x ----
    #pragma unroll
    for (int hl = 0; hl < 2; ++hl)
        #pragma unroll
        for (int ks = 0; ks < 2; ++ks) {
            half8 aw[4];
            #pragma unroll
            for (int mf = 0; mf < 4; ++mf)
                aw[mf] = wfv[((size_t)(hl * 2 + ks) * 4 + mf) * 64 + lane];
            #pragma unroll
            for (int mf = 0; mf < 4; ++mf)
                #pragma unroll
                for (int nf = 0; nf < 2; ++nf)
                    acc[mf][nf] = __builtin_amdgcn_mfma_f32_16x16x32_f16(aw[mf], xb[ks][nf], acc[mf][nf], 0, 0, 0);
        }

    if (!LAST) {
        // ---- epilogue: bias + relu, store xT + LDS (swizzled [c][t]) ----
        #pragma unroll
        for (int mf = 0; mf < 4; ++mf)
            #pragma unroll
            for (int nf = 0; nf < 2; ++nf) {
                int t = tw + nf * 16 + r;
                int tl = w * 32 + nf * 16 + r;
                half4 h4;
                #pragma unroll
                for (int reg = 0; reg < 4; ++reg) {
                    int o = mf * 16 + g * 4 + reg;
                    float val = fmaxf(acc[mf][nf][reg] + wb_l[o], 0.f);
                    h4[reg] = (_Float16)val;
                }
                *(half4*)&xT[((size_t)b * NPP + t) * 64 + mf * 16 + g * 4] = h4;
                #pragma unroll
                for (int reg = 0; reg < 4; ++reg) {
                    int c = mf * 16 + g * 4 + reg;
                    xls[(c << 7) + ((((tl << 1) ^ ((c & 15) << 4))) >> 1)] = h4[reg];
                }
            }
        __syncthreads();
        // ---- fwd DFT of new x: A from LDS, B=tabF; fixed-point atomic accumulate ----
        f32x4 dacc[4][2];
        #pragma unroll
        for (int cf = 0; cf < 4; ++cf)
            #pragma unroll
            for (int nf2 = 0; nf2 < 2; ++nf2) dacc[cf][nf2] = (f32x4){0.f, 0.f, 0.f, 0.f};
        #pragma unroll
        for (int ks = 0; ks < 4; ++ks) {
            half8 ax[4], bf2[2];
            #pragma unroll
            for (int cf = 0; cf < 4; ++cf) {
                int c = cf * 16 + r;
                int off = (ks * 64 + g * 16) ^ ((c & 15) << 4);
                ax[cf] = *(const half8*)&xls[(c << 7) + (off >> 1)];
            }
            int gs = ksb * 4 + ks;
            #pragma unroll
            for (int nf2 = 0; nf2 < 2; ++nf2)
                bf2[nf2] = tFv[((size_t)gs * 8 + w * 2 + nf2) * 64 + lane];
            #pragma unroll
            for (int cf = 0; cf < 4; ++cf)
                #pragma unroll
                for (int nf2 = 0; nf2 < 2; ++nf2)
                    dacc[cf][nf2] = __builtin_amdgcn_mfma_f32_16x16x32_f16(ax[cf], bf2[nf2], dacc[cf][nf2], 0, 0, 0);
        }
        unsigned long long* Xa = Xacc + (size_t)b * DV * 128;
        #pragma unroll
        for (int cf = 0; cf < 4; ++cf)
            #pragma unroll
            for (int nf2 = 0; nf2 < 2; ++nf2)
                #pragma unroll
                for (int reg = 0; reg < 4; ++reg) {
                    int c = cf * 16 + g * 4 + reg;
                    int m = w * 32 + nf2 * 16 + r;
                    long long qv = (long long)rintf(dacc[cf][nf2][reg] * FP_S);
                    atomicAdd(&Xa[(size_t)c * 128 + m], (unsigned long long)qv);
                }
    } else {
        float p0 = 0.f, p1 = 0.f;
        #pragma unroll
        for (int mf = 0; mf < 4; ++mf)
            #pragma unroll
            for (int reg = 0; reg < 4; ++reg) {
                int o = mf * 16 + g * 4 + reg;
                float qq = qw[o], bias = wb_l[o];
                p0 = fmaf(acc[mf][0][reg] + bias, qq, p0);
                p1 = fmaf(acc[mf][1][reg] + bias, qq, p1);
            }
        red[w][0][lane] = p0;
        red[w][1][lane] = p1;
        __syncthreads();
        if (tid < 128) {
            int w2 = tid >> 5, nf2 = (tid >> 4) & 1, c2 = tid & 15;
            float s2 = 0.f;
            #pragma unroll
            for (int g2 = 0; g2 < 4; ++g2) s2 += red[w2][nf2][g2 * 16 + c2];
            int t = ksb * 128 + w2 * 32 + nf2 * 16 + c2;
            if (t < NT) out[(size_t)b * NT + t] = s2 + qb[0];
        }
    }
}

extern "C" void kernel_launch(void* const* d_in, const int* in_sizes, int n_in,
                              void* d_out, int out_size, void* d_ws, size_t ws_size,
                              hipStream_t stream) {
    const float* v   = (const float*)d_in[0];
    const float* grd = (const float*)d_in[1];
    const float* pw  = (const float*)d_in[2];
    const float* pb  = (const float*)d_in[3];
    const float* fw  = (const float*)d_in[4];
    const float* ww  = (const float*)d_in[5];
    const float* wb  = (const float*)d_in[6];
    const float* qw  = (const float*)d_in[7];
    const float* qb  = (const float*)d_in[8];
    float* out = (float*)d_out;

    char* wsb = (char*)d_ws;
    _Float16* xT    = (_Float16*)(wsb + B_XT);
    _Float16* tabFb = (_Float16*)(wsb + B_TABF);
    _Float16* tabIb = (_Float16*)(wsb + B_TABI);
    _Float16* Wfrag = (_Float16*)(wsb + B_WFR);
    _Float16* zfrag = (_Float16*)(wsb + B_ZFR);
    unsigned long long* Xacc = (unsigned long long*)(wsb + B_XA);
    _Float16* Vpart = (_Float16*)(wsb + B_VP);
    float*    G     = (float*)(wsb + B_G);

    k_prep<<<(NPP * 64 + 255) / 256, 256, 0, stream>>>(tabFb, tabIb);
    k_prep_w<<<(NL * DV * DV + 255) / 256, 256, 0, stream>>>(ww, Wfrag);
    k_gd<<<128, 256, 0, stream>>>(grd, G);
    k_proj<<<dim3(65, NB), 256, 0, stream>>>(v, grd, pw, pb, xT);
    k_fdft_v<<<KSV, 256, 0, stream>>>(v, tabFb, Vpart);

    for (int l = 0; l < NL; ++l) {
        if (l == 0)
            k_spec0<<<dim3(4, NB), 256, 0, stream>>>(Vpart, G, pw, pb, fw, zfrag);
        else
            k_spec<<<dim3(4, NB), 256, 0, stream>>>(Xacc, fw + (size_t)l * DV * DV * 64 * 2, zfrag);
        // per-layer Wfrag block = 2(hilo) * 2(ks) * 4(mf) * 64(lane) * 8(j) = 8192 f16
        const _Float16* wf_l = Wfrag + (size_t)l * 8192;
        const float* wb_l = wb + (size_t)l * DV;
        if (l < NL - 1) {
            hipMemsetAsync(Xacc, 0, 4194304ull, stream);
            k_inv<false><<<dim3(KSB, NB), 256, 0, stream>>>(
                zfrag, tabIb, tabFb, wf_l, wb_l, qw, qb, xT, Xacc, out);
        } else {
            k_inv<true><<<dim3(KSB - 1, NB), 256, 0, stream>>>(
                zfrag, tabIb, tabFb, wf_l, wb_l, qw, qb, xT, Xacc, out);
        }
    }
}

// Round 7
// 503.413 us; speedup vs baseline: 1.6420x; 1.6420x over previous
//
#include <hip/hip_runtime.h>

#define NT    8192
#define NP    8200
#define NPP   8448          // 33*256 = 66*128 = 264*32
#define NB    64
#define DV    64
#define NL    4
#define KSB   33            // t-blocks for non-LAST k_inv (256 t each)
#define NSTEP 264           // 32-t K-steps
#define TFR   528           // 16-t fragments
#define KSV   24            // k-split for v-DFT (24*11 = 264 steps)
#define SPBV  11
#define PI2   6.28318530717958647692f

typedef _Float16 half8 __attribute__((ext_vector_type(8)));
typedef _Float16 half4 __attribute__((ext_vector_type(4)));
typedef float    f32x4 __attribute__((ext_vector_type(4)));

// ---------------- workspace layout (bytes) ----------------
// xT    : [NB][NPP][DV] f16                      69,206,016
// tabF  : [264][8][64][8] f16                     2,162,688
// tabI  : [4][528][64][8] f16 (alpha folded)      2,162,688
// Wfrag : [NL][2 hilo][2 ks][4 mf][64][8] f16       131,072
// zfrag : [NB][4][4][64][8] f16                   1,048,576
// xpf   : [KSB][NB][4 w][4 cf][2 nf][64][4] f16  34,603,008  (frag order)
// Vpart : [KSV][NB][128] f16                        393,216
// G     : [128] f32                                     512
static const size_t B_XT   = 0;
static const size_t B_TABF = 69206016ull;
static const size_t B_TABI = B_TABF + 2162688ull;
static const size_t B_WFR  = B_TABI + 2162688ull;
static const size_t B_ZFR  = B_WFR  + 131072ull;
static const size_t B_XPF  = B_ZFR  + 1048576ull;
static const size_t B_VP   = B_XPF  + 34603008ull;
static const size_t B_G    = B_VP   + 393216ull;

// ---------------- trig tables in MFMA fragment order ----------------
__global__ void k_prep(_Float16* __restrict__ tabF, _Float16* __restrict__ tabI) {
    int idx = blockIdx.x * 256 + threadIdx.x;
    if (idx >= NPP * 64) return;
    int t = idx >> 6, k = idx & 63;
    float c = 0.f, s = 0.f;
    if (t < NP) {
        int m = (int)(((long long)t * (long long)k) % NP);
        float th = (float)m * (PI2 / (float)NP);
        sincosf(th, &s, &c);
    }
    float al = (k == 0) ? (1.f / NP) : (2.f / NP);
    // tabF: B[k-dim=t][col=m]: step=t>>5, cf=m>>4, lane=(m&15)+16*((t>>3)&3), j=t&7
    {
        int gs = t >> 5, lh = (t >> 3) & 3, j = t & 7, cf = k >> 3;
        int m0 = 2 * k, m1 = 2 * k + 1;
        tabF[(((size_t)gs * 8 + cf) * 64 + (m0 & 15) + 16 * lh) * 8 + j] = (_Float16)c;
        tabF[(((size_t)gs * 8 + cf) * 64 + (m1 & 15) + 16 * lh) * 8 + j] = (_Float16)s;
    }
    // tabI: B[k-dim=m][col=t]: ks=m>>5, tf=t>>4, lane=(t&15)+16*((m>>3)&3), j=m&7
    {
        int tf = t >> 4, lt = t & 15;
        int m0 = 2 * k, m1 = 2 * k + 1;
        tabI[(((size_t)(m0 >> 5) * TFR + tf) * 64 + lt + 16 * ((m0 >> 3) & 3)) * 8 + (m0 & 7)] = (_Float16)(al * c);
        tabI[(((size_t)(m1 >> 5) * TFR + tf) * 64 + lt + 16 * ((m1 >> 3) & 3)) * 8 + (m1 & 7)] = (_Float16)(al * s);
    }
}

// ---------------- w_w hi/lo f16 in A-frag order ----------------
__global__ void k_prep_w(const float* __restrict__ ww, _Float16* __restrict__ Wfrag) {
    int idx = blockIdx.x * 256 + threadIdx.x;
    if (idx >= NL * DV * DV) return;
    int l = idx >> 12, cd = idx & 4095, c = cd >> 6, d = cd & 63;
    float wv = ww[((size_t)l * DV + c) * DV + d];     // A[row=d][k=c]
    _Float16 h = (_Float16)wv;
    _Float16 lo = (_Float16)(wv - (float)h);
    int ks = c >> 5, mf = d >> 4;
    int lane = (d & 15) + 16 * ((c >> 3) & 3), j = c & 7;
    Wfrag[((((size_t)l * 2 + 0) * 2 + ks) * 4 + mf) * 512 + (size_t)lane * 8 + j] = h;
    Wfrag[((((size_t)l * 2 + 1) * 2 + ks) * 4 + mf) * 512 + (size_t)lane * 8 + j] = lo;
}

// ---------------- G[m] = DFT(grid) ----------------
__global__ void k_gd(const float* __restrict__ grd, float* __restrict__ G) {
    __shared__ float rb[256];
    int m = blockIdx.x, k = m >> 1, comp = m & 1;
    int tid = threadIdx.x;
    float s = 0.f;
    for (int t = tid; t < NT; t += 256) {
        int mm = (int)(((long long)t * (long long)k) % NP);
        float th = (float)mm * (PI2 / (float)NP);
        float sn, cs; sincosf(th, &sn, &cs);
        s += grd[t] * (comp ? sn : cs);
    }
    rb[tid] = s; __syncthreads();
    for (int h = 128; h > 0; h >>= 1) { if (tid < h) rb[tid] += rb[tid + h]; __syncthreads(); }
    if (tid == 0) G[m] = rb[0];
}

// ---------------- initial projection -> xT[b][t][c] f16 ----------------
__global__ void k_proj(const float* __restrict__ v, const float* __restrict__ grd,
                       const float* __restrict__ pw, const float* __restrict__ pb,
                       _Float16* __restrict__ xT) {
    int b = blockIdx.y;
    int t = blockIdx.x * 128 + (threadIdx.x >> 1);
    int hf = threadIdx.x & 1;
    bool in = (t < NT);
    float vv = in ? v[(size_t)b * NT + t] : 0.f;
    float gg = in ? grd[t] : 0.f;
    _Float16 buf[32];
    #pragma unroll
    for (int q = 0; q < 32; ++q) {
        int c = hf * 32 + q;
        float val = in ? fmaf(vv, pw[c], fmaf(gg, pw[64 + c], pb[c])) : 0.f;
        buf[q] = (_Float16)val;
    }
    #pragma unroll
    for (int q = 0; q < 4; ++q)
        *(half8*)&xT[((size_t)b * NPP + t) * 64 + hf * 32 + q * 8] = *(half8*)&buf[q * 8];
}

// ---------------- partial DFT of v (A rows = batch) ----------------
__launch_bounds__(256)
__global__ void k_fdft_v(const float* __restrict__ v, const _Float16* __restrict__ tabF,
                         _Float16* __restrict__ Vp) {
    int ksb = blockIdx.x;
    int tid = threadIdx.x, w = tid >> 6, lane = tid & 63, g = lane >> 4, r = lane & 15;
    const half8* tFv = (const half8*)tabF;
    f32x4 acc[4][2];
    #pragma unroll
    for (int mf = 0; mf < 4; ++mf)
        #pragma unroll
        for (int nf = 0; nf < 2; ++nf) acc[mf][nf] = (f32x4){0.f, 0.f, 0.f, 0.f};
    for (int s = 0; s < SPBV; ++s) {
        int gs = ksb * SPBV + s;
        int t0 = gs * 32 + g * 8;
        half8 a[4];
        #pragma unroll
        for (int mf = 0; mf < 4; ++mf) {
            int brow = mf * 16 + r;
            half8 hv;
            if (t0 < NT) {
                const float4* pv = (const float4*)&v[(size_t)brow * NT + t0];
                float4 v0 = pv[0], v1 = pv[1];
                hv[0] = (_Float16)v0.x; hv[1] = (_Float16)v0.y; hv[2] = (_Float16)v0.z; hv[3] = (_Float16)v0.w;
                hv[4] = (_Float16)v1.x; hv[5] = (_Float16)v1.y; hv[6] = (_Float16)v1.z; hv[7] = (_Float16)v1.w;
            } else {
                #pragma unroll
                for (int j = 0; j < 8; ++j) hv[j] = (_Float16)0.f;
            }
            a[mf] = hv;
        }
        half8 bb[2];
        #pragma unroll
        for (int nf = 0; nf < 2; ++nf) bb[nf] = tFv[((size_t)gs * 8 + w * 2 + nf) * 64 + lane];
        #pragma unroll
        for (int mf = 0; mf < 4; ++mf)
            #pragma unroll
            for (int nf = 0; nf < 2; ++nf)
                acc[mf][nf] = __builtin_amdgcn_mfma_f32_16x16x32_f16(a[mf], bb[nf], acc[mf][nf], 0, 0, 0);
    }
    #pragma unroll
    for (int mf = 0; mf < 4; ++mf)
        #pragma unroll
        for (int nf = 0; nf < 2; ++nf)
            #pragma unroll
            for (int reg = 0; reg < 4; ++reg) {
                int brow = mf * 16 + g * 4 + reg;
                int m = w * 32 + nf * 16 + r;
                Vp[((size_t)ksb * NB + brow) * 128 + m] = (_Float16)acc[mf][nf][reg];
            }
}

// ---------------- spectral mix layer 0 (rank-2 X build) ----------------
__launch_bounds__(256)
__global__ void k_spec0(const _Float16* __restrict__ Vp, const float* __restrict__ G,
                        const float* __restrict__ pw, const float* __restrict__ pb,
                        const float* __restrict__ fw_l, _Float16* __restrict__ zfr) {
    __shared__ float Xs[64][32];
    __shared__ float Vs[32], Gs[32];
    int b = blockIdx.y, kq = blockIdx.x, tid = threadIdx.x;
    if (tid < 32) {
        int m = kq * 32 + tid;
        float ssum = 0.f;
        #pragma unroll
        for (int ks = 0; ks < KSV; ++ks) ssum += (float)Vp[((size_t)ks * NB + b) * 128 + m];
        Vs[tid] = ssum;
        Gs[tid] = G[m];
    }
    __syncthreads();
    #pragma unroll
    for (int q = 0; q < 8; ++q) {
        int flat = q * 256 + tid;
        int i = flat >> 5, ml = flat & 31;
        float xv = pw[i] * Vs[ml] + pw[64 + i] * Gs[ml];
        if (kq == 0 && ml == 0) xv += pb[i] * (float)NT;
        Xs[i][ml] = xv;
    }
    __syncthreads();
    #pragma unroll
    for (int q = 0; q < 4; ++q) {
        int flat = q * 256 + tid;
        int o = flat >> 4, kl = flat & 15;
        int k = kq * 16 + kl;
        float yr = 0.f, yi = 0.f;
        #pragma unroll 8
        for (int i = 0; i < 64; ++i) {
            float2 xv = *(const float2*)&Xs[i][2 * kl];
            float2 wv = *(const float2*)&fw_l[(((size_t)i * DV + o) * 64 + k) * 2];
            yr = fmaf(xv.x, wv.x, fmaf(xv.y, wv.y, yr));
            yi = fmaf(xv.x, wv.y, fmaf(-xv.y, wv.x, yi));
        }
        int mf = o >> 4, mm = 2 * kl, m1 = mm + 1;
        zfr[((((size_t)b * 4 + kq) * 4 + mf) * 64 + (o & 15) + 16 * (mm >> 3)) * 8 + (mm & 7)] = (_Float16)yr;
        zfr[((((size_t)b * 4 + kq) * 4 + mf) * 64 + (o & 15) + 16 * (m1 >> 3)) * 8 + (m1 & 7)] = (_Float16)(-yi);
    }
}

// ---------------- spectral mix layers 1..3 (frag-ordered partial reduce) ----------------
__launch_bounds__(256)
__global__ void k_spec(const _Float16* __restrict__ xpf, const float* __restrict__ fw_l,
                       _Float16* __restrict__ zfr) {
    __shared__ float Xs[64][32];
    int b = blockIdx.y, kq = blockIdx.x, tid = threadIdx.x;
    // reduce: thread owns 8 contiguous frag elems of the (b, w=kq) 2048-elem chunk
    float a8[8];
    #pragma unroll
    for (int e = 0; e < 8; ++e) a8[e] = 0.f;
    const half8* src = (const half8*)xpf;
    size_t base8 = (((size_t)b * 4 + kq) * 2048 + (size_t)tid * 8) >> 3;
    const size_t step8 = (size_t)NB * 4 * 2048 / 8;   // per-ksb stride in half8
    for (int ks = 0; ks < KSB; ++ks) {
        half8 vv = src[base8 + (size_t)ks * step8];
        #pragma unroll
        for (int e = 0; e < 8; ++e) a8[e] += (float)vv[e];
    }
    int cf = tid >> 6, nf2 = (tid >> 5) & 1, lane0 = (tid & 31) * 2;
    #pragma unroll
    for (int e = 0; e < 8; ++e) {
        int lane = lane0 + (e >> 2), reg = e & 3;
        int g = lane >> 4, r = lane & 15;
        Xs[cf * 16 + g * 4 + reg][nf2 * 16 + r] = a8[e];
    }
    __syncthreads();
    #pragma unroll
    for (int q = 0; q < 4; ++q) {
        int flat = q * 256 + tid;
        int o = flat >> 4, kl = flat & 15;
        int k = kq * 16 + kl;
        float yr = 0.f, yi = 0.f;
        #pragma unroll 8
        for (int i = 0; i < 64; ++i) {
            float2 xv = *(const float2*)&Xs[i][2 * kl];
            float2 wv = *(const float2*)&fw_l[(((size_t)i * DV + o) * 64 + k) * 2];
            yr = fmaf(xv.x, wv.x, fmaf(xv.y, wv.y, yr));
            yi = fmaf(xv.x, wv.y, fmaf(-xv.y, wv.x, yi));
        }
        int mf = o >> 4, mm = 2 * kl, m1 = mm + 1;
        zfr[((((size_t)b * 4 + kq) * 4 + mf) * 64 + (o & 15) + 16 * (mm >> 3)) * 8 + (mm & 7)] = (_Float16)yr;
        zfr[((((size_t)b * 4 + kq) * 4 + mf) * 64 + (o & 15) + 16 * (m1 >> 3)) * 8 + (m1 & 7)] = (_Float16)(-yi);
    }
}

// ---------------- fused: inverse DFT + local + bias + relu + fwd DFT ----------------
// non-LAST: grid (KSB, NB), 2 subtiles of 128 t per block; frag-ordered partial store.
// LAST: grid (64, NB), 1 subtile; q-contraction -> out.
template <bool LAST>
__launch_bounds__(256)
__global__ void k_inv(const _Float16* __restrict__ zfr, const _Float16* __restrict__ tabI,
                      const _Float16* __restrict__ tabF, const _Float16* __restrict__ Wl,
                      const float* __restrict__ wb_l, const float* __restrict__ qw,
                      const float* __restrict__ qb, _Float16* __restrict__ xT,
                      _Float16* __restrict__ xpf, float* __restrict__ out) {
    __shared__ _Float16 xls[64 * 128];    // [c][t-swizzled] 16 KiB
    __shared__ float red[4][2][64];
    int b = blockIdx.y, ksb = blockIdx.x;
    int tid = threadIdx.x, w = tid >> 6, lane = tid & 63;
    int g = lane >> 4, r = lane & 15;
    const half8* zfv = (const half8*)zfr;
    const half8* tIv = (const half8*)tabI;
    const half8* tFv = (const half8*)tabF;
    const half8* wfv = (const half8*)Wl;

    f32x4 dacc[4][2];
    #pragma unroll
    for (int cf = 0; cf < 4; ++cf)
        #pragma unroll
        for (int nf2 = 0; nf2 < 2; ++nf2) dacc[cf][nf2] = (f32x4){0.f, 0.f, 0.f, 0.f};

    const int nst = LAST ? 1 : 2;
    #pragma unroll 1
    for (int st = 0; st < nst; ++st) {
        int tw = (LAST ? ksb * 128 : ksb * 256 + st * 128) + w * 32;

        // ---- old-x B-frags (direct coalesced global) ----
        half8 xb[2][2];
        #pragma unroll
        for (int ks = 0; ks < 2; ++ks)
            #pragma unroll
            for (int nf = 0; nf < 2; ++nf)
                xb[ks][nf] = *(const half8*)&xT[((size_t)b * NPP + tw + nf * 16 + r) * 64 + ks * 32 + g * 8];

        f32x4 acc[4][2];
        #pragma unroll
        for (int mf = 0; mf < 4; ++mf)
            #pragma unroll
            for (int nf = 0; nf < 2; ++nf) acc[mf][nf] = (f32x4){0.f, 0.f, 0.f, 0.f};

        // ---- spectral: A=z, B=tabI ----
        #pragma unroll
        for (int ks4 = 0; ks4 < 4; ++ks4) {
            half8 az[4], bt[2];
            #pragma unroll
            for (int mf = 0; mf < 4; ++mf)
                az[mf] = zfv[(((size_t)b * 4 + ks4) * 4 + mf) * 64 + lane];
            #pragma unroll
            for (int nf = 0; nf < 2; ++nf)
                bt[nf] = tIv[((size_t)ks4 * TFR + (tw >> 4) + nf) * 64 + lane];
            #pragma unroll
            for (int mf = 0; mf < 4; ++mf)
                #pragma unroll
                for (int nf = 0; nf < 2; ++nf)
                    acc[mf][nf] = __builtin_amdgcn_mfma_f32_16x16x32_f16(az[mf], bt[nf], acc[mf][nf], 0, 0, 0);
        }
        // ---- local: (Whi + Wlo) * x ----
        #pragma unroll
        for (int hl = 0; hl < 2; ++hl)
            #pragma unroll
            for (int ks = 0; ks < 2; ++ks) {
                half8 aw[4];
                #pragma unroll
                for (int mf = 0; mf < 4; ++mf)
                    aw[mf] = wfv[((size_t)(hl * 2 + ks) * 4 + mf) * 64 + lane];
                #pragma unroll
                for (int mf = 0; mf < 4; ++mf)
                    #pragma unroll
                    for (int nf = 0; nf < 2; ++nf)
                        acc[mf][nf] = __builtin_amdgcn_mfma_f32_16x16x32_f16(aw[mf], xb[ks][nf], acc[mf][nf], 0, 0, 0);
            }

        if (!LAST) {
            // ---- epilogue: bias + relu, store xT + LDS (swizzled [c][t]) ----
            #pragma unroll
            for (int mf = 0; mf < 4; ++mf)
                #pragma unroll
                for (int nf = 0; nf < 2; ++nf) {
                    int t = tw + nf * 16 + r;
                    int tl = w * 32 + nf * 16 + r;
                    half4 h4;
                    #pragma unroll
                    for (int reg = 0; reg < 4; ++reg) {
                        int o = mf * 16 + g * 4 + reg;
                        float val = fmaxf(acc[mf][nf][reg] + wb_l[o], 0.f);
                        h4[reg] = (_Float16)val;
                    }
                    *(half4*)&xT[((size_t)b * NPP + t) * 64 + mf * 16 + g * 4] = h4;
                    #pragma unroll
                    for (int reg = 0; reg < 4; ++reg) {
                        int c = mf * 16 + g * 4 + reg;
                        xls[(c << 7) + ((((tl << 1) ^ ((c & 15) << 4))) >> 1)] = h4[reg];
                    }
                }
            __syncthreads();
            // ---- fwd DFT of new x: A from LDS, B=tabF ----
            #pragma unroll
            for (int ks = 0; ks < 4; ++ks) {
                half8 ax[4], bf2[2];
                #pragma unroll
                for (int cf = 0; cf < 4; ++cf) {
                    int c = cf * 16 + r;
                    int off = (ks * 64 + g * 16) ^ ((c & 15) << 4);
                    ax[cf] = *(const half8*)&xls[(c << 7) + (off >> 1)];
                }
                int gs = ksb * 8 + st * 4 + ks;
                #pragma unroll
                for (int nf2 = 0; nf2 < 2; ++nf2)
                    bf2[nf2] = tFv[((size_t)gs * 8 + w * 2 + nf2) * 64 + lane];
                #pragma unroll
                for (int cf = 0; cf < 4; ++cf)
                    #pragma unroll
                    for (int nf2 = 0; nf2 < 2; ++nf2)
                        dacc[cf][nf2] = __builtin_amdgcn_mfma_f32_16x16x32_f16(ax[cf], bf2[nf2], dacc[cf][nf2], 0, 0, 0);
            }
            __syncthreads();
        } else {
            float p0 = 0.f, p1 = 0.f;
            #pragma unroll
            for (int mf = 0; mf < 4; ++mf)
                #pragma unroll
                for (int reg = 0; reg < 4; ++reg) {
                    int o = mf * 16 + g * 4 + reg;
                    float qq = qw[o], bias = wb_l[o];
                    p0 = fmaf(acc[mf][0][reg] + bias, qq, p0);
                    p1 = fmaf(acc[mf][1][reg] + bias, qq, p1);
                }
            red[w][0][lane] = p0;
            red[w][1][lane] = p1;
            __syncthreads();
            if (tid < 128) {
                int w2 = tid >> 5, nf2 = (tid >> 4) & 1, c2 = tid & 15;
                float s2 = 0.f;
                #pragma unroll
                for (int g2 = 0; g2 < 4; ++g2) s2 += red[w2][nf2][g2 * 16 + c2];
                int t = ksb * 128 + w2 * 32 + nf2 * 16 + c2;
                if (t < NT) out[(size_t)b * NT + t] = s2 + qb[0];
            }
        }
    }
    if (!LAST) {
        // frag-ordered partial store: lane-contiguous half4, wave = 512B contiguous
        _Float16* xp = xpf + (((size_t)ksb * NB + b) * 4 + w) * 2048;
        #pragma unroll
        for (int cf = 0; cf < 4; ++cf)
            #pragma unroll
            for (int nf2 = 0; nf2 < 2; ++nf2) {
                half4 h4;
                #pragma unroll
                for (int reg = 0; reg < 4; ++reg) h4[reg] = (_Float16)dacc[cf][nf2][reg];
                *(half4*)&xp[(cf * 2 + nf2) * 256 + lane * 4] = h4;
            }
    }
}

extern "C" void kernel_launch(void* const* d_in, const int* in_sizes, int n_in,
                              void* d_out, int out_size, void* d_ws, size_t ws_size,
                              hipStream_t stream) {
    const float* v   = (const float*)d_in[0];
    const float* grd = (const float*)d_in[1];
    const float* pw  = (const float*)d_in[2];
    const float* pb  = (const float*)d_in[3];
    const float* fw  = (const float*)d_in[4];
    const float* ww  = (const float*)d_in[5];
    const float* wb  = (const float*)d_in[6];
    const float* qw  = (const float*)d_in[7];
    const float* qb  = (const float*)d_in[8];
    float* out = (float*)d_out;

    char* wsb = (char*)d_ws;
    _Float16* xT    = (_Float16*)(wsb + B_XT);
    _Float16* tabFb = (_Float16*)(wsb + B_TABF);
    _Float16* tabIb = (_Float16*)(wsb + B_TABI);
    _Float16* Wfrag = (_Float16*)(wsb + B_WFR);
    _Float16* zfrag = (_Float16*)(wsb + B_ZFR);
    _Float16* xpf   = (_Float16*)(wsb + B_XPF);
    _Float16* Vpart = (_Float16*)(wsb + B_VP);
    float*    G     = (float*)(wsb + B_G);

    k_prep<<<(NPP * 64 + 255) / 256, 256, 0, stream>>>(tabFb, tabIb);
    k_prep_w<<<(NL * DV * DV + 255) / 256, 256, 0, stream>>>(ww, Wfrag);
    k_gd<<<128, 256, 0, stream>>>(grd, G);
    k_proj<<<dim3(NPP / 128, NB), 256, 0, stream>>>(v, grd, pw, pb, xT);
    k_fdft_v<<<KSV, 256, 0, stream>>>(v, tabFb, Vpart);

    for (int l = 0; l < NL; ++l) {
        if (l == 0)
            k_spec0<<<dim3(4, NB), 256, 0, stream>>>(Vpart, G, pw, pb, fw, zfrag);
        else
            k_spec<<<dim3(4, NB), 256, 0, stream>>>(xpf, fw + (size_t)l * DV * DV * 64 * 2, zfrag);
        // per-layer Wfrag block = 2(hilo) * 2(ks) * 4(mf) * 64(lane) * 8(j) = 8192 f16
        const _Float16* wf_l = Wfrag + (size_t)l * 8192;
        const float* wb_l = wb + (size_t)l * DV;
        if (l < NL - 1)
            k_inv<false><<<dim3(KSB, NB), 256, 0, stream>>>(
                zfrag, tabIb, tabFb, wf_l, wb_l, qw, qb, xT, xpf, out);
        else
            k_inv<true><<<dim3(NT / 128, NB), 256, 0, stream>>>(
                zfrag, tabIb, tabFb, wf_l, wb_l, qw, qb, xT, xpf, out);
    }
}

// Round 8
// 375.318 us; speedup vs baseline: 2.2024x; 1.3413x over previous
//
#include <hip/hip_runtime.h>

#define NT    8192
#define NP    8200
#define NPP   8320          // 65*128 = 260*32 = 520*16
#define NB    64
#define DV    64
#define NL    4
#define TFR   520
#define KSP   20            // t-splits for standalone fwd-DFT (20*13 = 260 steps)
#define SPB   13
#define PI2   6.28318530717958647692f

typedef _Float16 half8 __attribute__((ext_vector_type(8)));
typedef _Float16 half4 __attribute__((ext_vector_type(4)));
typedef float    f32x4 __attribute__((ext_vector_type(4)));

// ---------------- workspace layout (bytes) ----------------
// xT    : [NB][NPP][DV] f16                68,157,440
// tabF  : [260][8][64][8] f16               2,129,920
// tabI  : [4][520][64][8] f16 (alpha)       2,129,920
// Wfrag : [NL][2][2][4][64][8] f16            131,072
// zfrag : [NB][4][4][64][8] f16             1,048,576
// xpf   : [KSP][NB][4][2048] f16           20,971,520  (frag order)
// Vpart : [KSP][NB][128] f16                  327,680
// G     : [128] f32                               512
static const size_t B_XT   = 0;
static const size_t B_TABF = 68157440ull;
static const size_t B_TABI = B_TABF + 2129920ull;
static const size_t B_WFR  = B_TABI + 2129920ull;
static const size_t B_ZFR  = B_WFR  + 131072ull;
static const size_t B_XPF  = B_ZFR  + 1048576ull;
static const size_t B_VP   = B_XPF  + 20971520ull;
static const size_t B_G    = B_VP   + 327680ull;

// ---------------- trig tables in MFMA fragment order ----------------
__global__ void k_prep(_Float16* __restrict__ tabF, _Float16* __restrict__ tabI) {
    int idx = blockIdx.x * 256 + threadIdx.x;
    if (idx >= NPP * 64) return;
    int t = idx >> 6, k = idx & 63;
    float c = 0.f, s = 0.f;
    if (t < NP) {
        int m = (int)(((long long)t * (long long)k) % NP);
        float th = (float)m * (PI2 / (float)NP);
        sincosf(th, &s, &c);
    }
    float al = (k == 0) ? (1.f / NP) : (2.f / NP);
    {   // tabF: B[k=t][col=m]
        int gs = t >> 5, lh = (t >> 3) & 3, j = t & 7;
        int m0 = 2 * k, m1 = 2 * k + 1;
        tabF[(((size_t)gs * 8 + (m0 >> 4)) * 64 + (m0 & 15) + 16 * lh) * 8 + j] = (_Float16)c;
        tabF[(((size_t)gs * 8 + (m1 >> 4)) * 64 + (m1 & 15) + 16 * lh) * 8 + j] = (_Float16)s;
    }
    {   // tabI: B[k=m][col=t], alpha folded
        int tf = t >> 4, lt = t & 15;
        int m0 = 2 * k, m1 = 2 * k + 1;
        tabI[(((size_t)(m0 >> 5) * TFR + tf) * 64 + lt + 16 * ((m0 >> 3) & 3)) * 8 + (m0 & 7)] = (_Float16)(al * c);
        tabI[(((size_t)(m1 >> 5) * TFR + tf) * 64 + lt + 16 * ((m1 >> 3) & 3)) * 8 + (m1 & 7)] = (_Float16)(al * s);
    }
}

// ---------------- w_w hi/lo f16 in A-frag order ----------------
__global__ void k_prep_w(const float* __restrict__ ww, _Float16* __restrict__ Wfrag) {
    int idx = blockIdx.x * 256 + threadIdx.x;
    if (idx >= NL * DV * DV) return;
    int l = idx >> 12, cd = idx & 4095, c = cd >> 6, d = cd & 63;
    float wv = ww[((size_t)l * DV + c) * DV + d];     // A[row=d][k=c]
    _Float16 h = (_Float16)wv;
    _Float16 lo = (_Float16)(wv - (float)h);
    int ks = c >> 5, mf = d >> 4;
    int lane = (d & 15) + 16 * ((c >> 3) & 3), j = c & 7;
    Wfrag[((((size_t)l * 2 + 0) * 2 + ks) * 4 + mf) * 512 + (size_t)lane * 8 + j] = h;
    Wfrag[((((size_t)l * 2 + 1) * 2 + ks) * 4 + mf) * 512 + (size_t)lane * 8 + j] = lo;
}

// ---------------- G[m] = DFT(grid) ----------------
__global__ void k_gd(const float* __restrict__ grd, float* __restrict__ G) {
    __shared__ float rb[256];
    int m = blockIdx.x, k = m >> 1, comp = m & 1;
    int tid = threadIdx.x;
    float s = 0.f;
    for (int t = tid; t < NT; t += 256) {
        int mm = (int)(((long long)t * (long long)k) % NP);
        float th = (float)mm * (PI2 / (float)NP);
        float sn, cs; sincosf(th, &sn, &cs);
        s += grd[t] * (comp ? sn : cs);
    }
    rb[tid] = s; __syncthreads();
    for (int h = 128; h > 0; h >>= 1) { if (tid < h) rb[tid] += rb[tid + h]; __syncthreads(); }
    if (tid == 0) G[m] = rb[0];
}

// ---------------- initial projection -> xT[b][t][c] f16 ----------------
__global__ void k_proj(const float* __restrict__ v, const float* __restrict__ grd,
                       const float* __restrict__ pw, const float* __restrict__ pb,
                       _Float16* __restrict__ xT) {
    int b = blockIdx.y;
    int t = blockIdx.x * 128 + (threadIdx.x >> 1);
    int hf = threadIdx.x & 1;
    bool in = (t < NT);
    float vv = in ? v[(size_t)b * NT + t] : 0.f;
    float gg = in ? grd[t] : 0.f;
    _Float16 buf[32];
    #pragma unroll
    for (int q = 0; q < 32; ++q) {
        int c = hf * 32 + q;
        float val = in ? fmaf(vv, pw[c], fmaf(gg, pw[64 + c], pb[c])) : 0.f;
        buf[q] = (_Float16)val;
    }
    #pragma unroll
    for (int q = 0; q < 4; ++q)
        *(half8*)&xT[((size_t)b * NPP + t) * 64 + hf * 32 + q * 8] = *(half8*)&buf[q * 8];
}

// ---------------- partial DFT of v (A rows = batch) ----------------
__launch_bounds__(256)
__global__ void k_fdft_v(const float* __restrict__ v, const _Float16* __restrict__ tabF,
                         _Float16* __restrict__ Vp) {
    int ksb = blockIdx.x;
    int tid = threadIdx.x, w = tid >> 6, lane = tid & 63, g = lane >> 4, r = lane & 15;
    const half8* tFv = (const half8*)tabF;
    f32x4 acc[4][2];
    #pragma unroll
    for (int mf = 0; mf < 4; ++mf)
        #pragma unroll
        for (int nf = 0; nf < 2; ++nf) acc[mf][nf] = (f32x4){0.f, 0.f, 0.f, 0.f};
    for (int s = 0; s < SPB; ++s) {
        int gs = ksb * SPB + s;
        int t0 = gs * 32 + g * 8;
        half8 a[4];
        #pragma unroll
        for (int mf = 0; mf < 4; ++mf) {
            int brow = mf * 16 + r;
            half8 hv;
            if (t0 < NT) {
                const float4* pv = (const float4*)&v[(size_t)brow * NT + t0];
                float4 v0 = pv[0], v1 = pv[1];
                hv[0] = (_Float16)v0.x; hv[1] = (_Float16)v0.y; hv[2] = (_Float16)v0.z; hv[3] = (_Float16)v0.w;
                hv[4] = (_Float16)v1.x; hv[5] = (_Float16)v1.y; hv[6] = (_Float16)v1.z; hv[7] = (_Float16)v1.w;
            } else {
                #pragma unroll
                for (int j = 0; j < 8; ++j) hv[j] = (_Float16)0.f;
            }
            a[mf] = hv;
        }
        half8 bb[2];
        #pragma unroll
        for (int nf = 0; nf < 2; ++nf) bb[nf] = tFv[((size_t)gs * 8 + w * 2 + nf) * 64 + lane];
        #pragma unroll
        for (int mf = 0; mf < 4; ++mf)
            #pragma unroll
            for (int nf = 0; nf < 2; ++nf)
                acc[mf][nf] = __builtin_amdgcn_mfma_f32_16x16x32_f16(a[mf], bb[nf], acc[mf][nf], 0, 0, 0);
    }
    #pragma unroll
    for (int mf = 0; mf < 4; ++mf)
        #pragma unroll
        for (int nf = 0; nf < 2; ++nf)
            #pragma unroll
            for (int reg = 0; reg < 4; ++reg) {
                int brow = mf * 16 + g * 4 + reg;
                int m = w * 32 + nf * 16 + r;
                Vp[((size_t)ksb * NB + brow) * 128 + m] = (_Float16)acc[mf][nf][reg];
            }
}

// ---------------- standalone fwd DFT of xT: LDS-staged A, frag-order partials ----------------
__launch_bounds__(256)
__global__ void k_fdft(const _Float16* __restrict__ xT, const _Float16* __restrict__ tabF,
                       _Float16* __restrict__ xpf) {
    __shared__ _Float16 xls[2048];   // [64c][32t] swizzled, 4 KiB
    int sb = blockIdx.x, b = blockIdx.y;
    int tid = threadIdx.x, w = tid >> 6, lane = tid & 63, g = lane >> 4, r = lane & 15;
    const half8* tFv = (const half8*)tabF;
    f32x4 acc[4][2];
    #pragma unroll
    for (int cf = 0; cf < 4; ++cf)
        #pragma unroll
        for (int nf = 0; nf < 2; ++nf) acc[cf][nf] = (f32x4){0.f, 0.f, 0.f, 0.f};
    int tl = tid >> 3, c0 = (tid & 7) * 8;
    #pragma unroll 1
    for (int s = 0; s < SPB; ++s) {
        int gs = sb * SPB + s;
        half8 vv = *(const half8*)&xT[((size_t)b * NPP + gs * 32 + tl) * 64 + c0];
        __syncthreads();   // protect previous iteration's reads
        #pragma unroll
        for (int j = 0; j < 8; ++j) {
            int c = c0 + j;
            xls[c * 32 + (tl ^ (((c >> 3) & 3) << 3))] = vv[j];
        }
        __syncthreads();
        half8 a[4], bb[2];
        #pragma unroll
        for (int cf = 0; cf < 4; ++cf) {
            int c = cf * 16 + r;
            a[cf] = *(const half8*)&xls[c * 32 + ((g * 8) ^ ((((c >> 3) & 3)) << 3))];
        }
        #pragma unroll
        for (int nf = 0; nf < 2; ++nf) bb[nf] = tFv[((size_t)gs * 8 + w * 2 + nf) * 64 + lane];
        #pragma unroll
        for (int cf = 0; cf < 4; ++cf)
            #pragma unroll
            for (int nf = 0; nf < 2; ++nf)
                acc[cf][nf] = __builtin_amdgcn_mfma_f32_16x16x32_f16(a[cf], bb[nf], acc[cf][nf], 0, 0, 0);
    }
    // frag-ordered partial store: lane-contiguous half4, wave = 512B contiguous
    _Float16* xp = xpf + (((size_t)sb * NB + b) * 4 + w) * 2048;
    #pragma unroll
    for (int cf = 0; cf < 4; ++cf)
        #pragma unroll
        for (int nf = 0; nf < 2; ++nf) {
            half4 h4;
            #pragma unroll
            for (int reg = 0; reg < 4; ++reg) h4[reg] = (_Float16)acc[cf][nf][reg];
            *(half4*)&xp[(cf * 2 + nf) * 256 + lane * 4] = h4;
        }
}

// ---------------- spectral mix layer 0 (rank-2 X build) ----------------
__launch_bounds__(256)
__global__ void k_spec0(const _Float16* __restrict__ Vp, const float* __restrict__ G,
                        const float* __restrict__ pw, const float* __restrict__ pb,
                        const float* __restrict__ fw_l, _Float16* __restrict__ zfr) {
    __shared__ float Xs[64][32];
    __shared__ float Vs[32], Gs[32];
    int b = blockIdx.y, kq = blockIdx.x, tid = threadIdx.x;
    if (tid < 32) {
        int m = kq * 32 + tid;
        float ssum = 0.f;
        #pragma unroll
        for (int ks = 0; ks < KSP; ++ks) ssum += (float)Vp[((size_t)ks * NB + b) * 128 + m];
        Vs[tid] = ssum;
        Gs[tid] = G[m];
    }
    __syncthreads();
    #pragma unroll
    for (int q = 0; q < 8; ++q) {
        int flat = q * 256 + tid;
        int i = flat >> 5, ml = flat & 31;
        float xv = pw[i] * Vs[ml] + pw[64 + i] * Gs[ml];
        if (kq == 0 && ml == 0) xv += pb[i] * (float)NT;
        Xs[i][ml] = xv;
    }
    __syncthreads();
    #pragma unroll
    for (int q = 0; q < 4; ++q) {
        int flat = q * 256 + tid;
        int o = flat >> 4, kl = flat & 15;
        int k = kq * 16 + kl;
        float yr = 0.f, yi = 0.f;
        #pragma unroll 8
        for (int i = 0; i < 64; ++i) {
            float2 xv = *(const float2*)&Xs[i][2 * kl];
            float2 wv = *(const float2*)&fw_l[(((size_t)i * DV + o) * 64 + k) * 2];
            yr = fmaf(xv.x, wv.x, fmaf(xv.y, wv.y, yr));
            yi = fmaf(xv.x, wv.y, fmaf(-xv.y, wv.x, yi));
        }
        int mf = o >> 4, mm = 2 * kl, m1 = mm + 1;
        zfr[((((size_t)b * 4 + kq) * 4 + mf) * 64 + (o & 15) + 16 * (mm >> 3)) * 8 + (mm & 7)] = (_Float16)yr;
        zfr[((((size_t)b * 4 + kq) * 4 + mf) * 64 + (o & 15) + 16 * (m1 >> 3)) * 8 + (m1 & 7)] = (_Float16)(-yi);
    }
}

// ---------------- spectral mix layers 1..3 (frag-ordered partial reduce) ----------------
__launch_bounds__(256)
__global__ void k_spec(const _Float16* __restrict__ xpf, const float* __restrict__ fw_l,
                       _Float16* __restrict__ zfr) {
    __shared__ float Xs[64][32];
    int b = blockIdx.y, kq = blockIdx.x, tid = threadIdx.x;
    float a8[8];
    #pragma unroll
    for (int e = 0; e < 8; ++e) a8[e] = 0.f;
    const half8* src = (const half8*)xpf;
    size_t base8 = ((size_t)b * 4 + kq) * 256 + tid;
    const size_t step8 = (size_t)NB * 4 * 256;
    for (int ks = 0; ks < KSP; ++ks) {
        half8 vv = src[base8 + (size_t)ks * step8];
        #pragma unroll
        for (int e = 0; e < 8; ++e) a8[e] += (float)vv[e];
    }
    int cf = tid >> 6, nf2 = (tid >> 5) & 1, lane0 = (tid & 31) * 2;
    #pragma unroll
    for (int e = 0; e < 8; ++e) {
        int lane = lane0 + (e >> 2), reg = e & 3;
        int g = lane >> 4, r = lane & 15;
        Xs[cf * 16 + g * 4 + reg][nf2 * 16 + r] = a8[e];
    }
    __syncthreads();
    #pragma unroll
    for (int q = 0; q < 4; ++q) {
        int flat = q * 256 + tid;
        int o = flat >> 4, kl = flat & 15;
        int k = kq * 16 + kl;
        float yr = 0.f, yi = 0.f;
        #pragma unroll 8
        for (int i = 0; i < 64; ++i) {
            float2 xv = *(const float2*)&Xs[i][2 * kl];
            float2 wv = *(const float2*)&fw_l[(((size_t)i * DV + o) * 64 + k) * 2];
            yr = fmaf(xv.x, wv.x, fmaf(xv.y, wv.y, yr));
            yi = fmaf(xv.x, wv.y, fmaf(-xv.y, wv.x, yi));
        }
        int mf = o >> 4, mm = 2 * kl, m1 = mm + 1;
        zfr[((((size_t)b * 4 + kq) * 4 + mf) * 64 + (o & 15) + 16 * (mm >> 3)) * 8 + (mm & 7)] = (_Float16)yr;
        zfr[((((size_t)b * 4 + kq) * 4 + mf) * 64 + (o & 15) + 16 * (m1 >> 3)) * 8 + (m1 & 7)] = (_Float16)(-yi);
    }
}

// ---------------- inverse DFT + local + bias (+relu | +q_w reduce), straight-line ----------------
template <bool LAST>
__launch_bounds__(256)
__global__ void k_inv(const _Float16* __restrict__ zfr, const _Float16* __restrict__ tabI,
                      const _Float16* __restrict__ Wl, const float* __restrict__ wb_l,
                      const float* __restrict__ qw, const float* __restrict__ qb,
                      _Float16* __restrict__ xT, float* __restrict__ out) {
    __shared__ _Float16 xlt[128 * 64];   // t-major swizzled, 16 KiB (non-LAST)
    __shared__ float red[4][2][64];      // LAST
    int b = blockIdx.y, ksb = blockIdx.x;
    int tid = threadIdx.x, w = tid >> 6, lane = tid & 63;
    int g = lane >> 4, r = lane & 15;
    int tw = ksb * 128 + w * 32;
    const half8* zfv = (const half8*)zfr;
    const half8* tIv = (const half8*)tabI;
    const half8* wfv = (const half8*)Wl;

    // ---- old-x B-frags (direct coalesced global) ----
    half8 xb[2][2];
    #pragma unroll
    for (int ks = 0; ks < 2; ++ks)
        #pragma unroll
        for (int nf = 0; nf < 2; ++nf)
            xb[ks][nf] = *(const half8*)&xT[((size_t)b * NPP + tw + nf * 16 + r) * 64 + ks * 32 + g * 8];

    f32x4 acc[4][2];
    #pragma unroll
    for (int mf = 0; mf < 4; ++mf)
        #pragma unroll
        for (int nf = 0; nf < 2; ++nf) acc[mf][nf] = (f32x4){0.f, 0.f, 0.f, 0.f};

    // ---- spectral: A=z, B=tabI ----
    #pragma unroll
    for (int ks4 = 0; ks4 < 4; ++ks4) {
        half8 az[4], bt[2];
        #pragma unroll
        for (int mf = 0; mf < 4; ++mf)
            az[mf] = zfv[(((size_t)b * 4 + ks4) * 4 + mf) * 64 + lane];
        #pragma unroll
        for (int nf = 0; nf < 2; ++nf)
            bt[nf] = tIv[((size_t)ks4 * TFR + (tw >> 4) + nf) * 64 + lane];
        #pragma unroll
        for (int mf = 0; mf < 4; ++mf)
            #pragma unroll
            for (int nf = 0; nf < 2; ++nf)
                acc[mf][nf] = __builtin_amdgcn_mfma_f32_16x16x32_f16(az[mf], bt[nf], acc[mf][nf], 0, 0, 0);
    }
    // ---- local: (Whi + Wlo) * x ----
    #pragma unroll
    for (int hl = 0; hl < 2; ++hl)
        #pragma unroll
        for (int ks = 0; ks < 2; ++ks) {
            half8 aw[4];
            #pragma unroll
            for (int mf = 0; mf < 4; ++mf)
                aw[mf] = wfv[((size_t)(hl * 2 + ks) * 4 + mf) * 64 + lane];
            #pragma unroll
            for (int mf = 0; mf < 4; ++mf)
                #pragma unroll
                for (int nf = 0; nf < 2; ++nf)
                    acc[mf][nf] = __builtin_amdgcn_mfma_f32_16x16x32_f16(aw[mf], xb[ks][nf], acc[mf][nf], 0, 0, 0);
        }

    if (!LAST) {
        // ---- epilogue: bias + relu -> swizzled t-major LDS -> coalesced xT store ----
        #pragma unroll
        for (int mf = 0; mf < 4; ++mf)
            #pragma unroll
            for (int nf = 0; nf < 2; ++nf) {
                int tl = w * 32 + nf * 16 + r;
                half4 h4;
                #pragma unroll
                for (int reg = 0; reg < 4; ++reg) {
                    int o = mf * 16 + g * 4 + reg;
                    h4[reg] = (_Float16)fmaxf(acc[mf][nf][reg] + wb_l[o], 0.f);
                }
                int idx = tl * 64 + ((mf * 16 + g * 4) ^ ((tl & 7) << 3));
                *(half4*)&xlt[idx] = h4;
            }
        __syncthreads();
        #pragma unroll
        for (int it = 0; it < 4; ++it) {
            int flat = it * 256 + tid;
            int t = flat >> 3, k = flat & 7;
            half8 vv = *(const half8*)&xlt[t * 64 + ((k * 8) ^ ((t & 7) << 3))];
            *(half8*)&xT[((size_t)b * NPP + ksb * 128 + t) * 64 + k * 8] = vv;
        }
    } else {
        float p0 = 0.f, p1 = 0.f;
        #pragma unroll
        for (int mf = 0; mf < 4; ++mf)
            #pragma unroll
            for (int reg = 0; reg < 4; ++reg) {
                int o = mf * 16 + g * 4 + reg;
                float qq = qw[o], bias = wb_l[o];
                p0 = fmaf(acc[mf][0][reg] + bias, qq, p0);
                p1 = fmaf(acc[mf][1][reg] + bias, qq, p1);
            }
        red[w][0][lane] = p0;
        red[w][1][lane] = p1;
        __syncthreads();
        if (tid < 128) {
            int w2 = tid >> 5, nf2 = (tid >> 4) & 1, c2 = tid & 15;
            float s2 = 0.f;
            #pragma unroll
            for (int g2 = 0; g2 < 4; ++g2) s2 += red[w2][nf2][g2 * 16 + c2];
            int t = ksb * 128 + w2 * 32 + nf2 * 16 + c2;
            if (t < NT) out[(size_t)b * NT + t] = s2 + qb[0];
        }
    }
}

extern "C" void kernel_launch(void* const* d_in, const int* in_sizes, int n_in,
                              void* d_out, int out_size, void* d_ws, size_t ws_size,
                              hipStream_t stream) {
    const float* v   = (const float*)d_in[0];
    const float* grd = (const float*)d_in[1];
    const float* pw  = (const float*)d_in[2];
    const float* pb  = (const float*)d_in[3];
    const float* fw  = (const float*)d_in[4];
    const float* ww  = (const float*)d_in[5];
    const float* wb  = (const float*)d_in[6];
    const float* qw  = (const float*)d_in[7];
    const float* qb  = (const float*)d_in[8];
    float* out = (float*)d_out;

    char* wsb = (char*)d_ws;
    _Float16* xT    = (_Float16*)(wsb + B_XT);
    _Float16* tabFb = (_Float16*)(wsb + B_TABF);
    _Float16* tabIb = (_Float16*)(wsb + B_TABI);
    _Float16* Wfrag = (_Float16*)(wsb + B_WFR);
    _Float16* zfrag = (_Float16*)(wsb + B_ZFR);
    _Float16* xpf   = (_Float16*)(wsb + B_XPF);
    _Float16* Vpart = (_Float16*)(wsb + B_VP);
    float*    G     = (float*)(wsb + B_G);

    k_prep<<<(NPP * 64 + 255) / 256, 256, 0, stream>>>(tabFb, tabIb);
    k_prep_w<<<(NL * DV * DV + 255) / 256, 256, 0, stream>>>(ww, Wfrag);
    k_gd<<<128, 256, 0, stream>>>(grd, G);
    k_proj<<<dim3(NPP / 128, NB), 256, 0, stream>>>(v, grd, pw, pb, xT);
    k_fdft_v<<<KSP, 256, 0, stream>>>(v, tabFb, Vpart);

    for (int l = 0; l < NL; ++l) {
        if (l == 0) {
            k_spec0<<<dim3(4, NB), 256, 0, stream>>>(Vpart, G, pw, pb, fw, zfrag);
        } else {
            k_fdft<<<dim3(KSP, NB), 256, 0, stream>>>(xT, tabFb, xpf);
            k_spec<<<dim3(4, NB), 256, 0, stream>>>(xpf, fw + (size_t)l * DV * DV * 64 * 2, zfrag);
        }
        const _Float16* wf_l = Wfrag + (size_t)l * 8192;   // 2*2*4*64*8 per layer
        const float* wb_l = wb + (size_t)l * DV;
        if (l < NL - 1)
            k_inv<false><<<dim3(NPP / 128, NB), 256, 0, stream>>>(
                zfrag, tabIb, wf_l, wb_l, qw, qb, xT, out);
        else
            k_inv<true><<<dim3(NT / 128, NB), 256, 0, stream>>>(
                zfrag, tabIb, wf_l, wb_l, qw, qb, xT, out);
    }
}

// Round 9
// 305.611 us; speedup vs baseline: 2.7048x; 1.2281x over previous
//
#include <hip/hip_runtime.h>

#define NT    8192
#define NP    8200
#define NPP   8320          // 65*128 = 260*32 = 520*16
#define NB    64
#define DV    64
#define NL    4
#define TFR   520
#define KSP   20            // t-splits for standalone fwd-DFT (20*13 = 260 steps)
#define SPB   13
#define PI2   6.28318530717958647692f

typedef _Float16 half8 __attribute__((ext_vector_type(8)));
typedef _Float16 half4 __attribute__((ext_vector_type(4)));
typedef float    f32x4 __attribute__((ext_vector_type(4)));

// ---------------- workspace layout (bytes) ----------------
// xT    : [NB][NPP][DV] f16                68,157,440
// tabF  : [260][8][64][8] f16               2,129,920
// tabI  : [4][520][64][8] f16 (alpha)       2,129,920
// Wfrag : [NL][2][2][4][64][8] f16            131,072
// zfrag : [NB][4][4][64][8] f16             1,048,576
// xpf   : [KSP][NB][4][2048] f16           20,971,520  (frag order)
// Vpart : [KSP][NB][128] f16                  327,680
// G     : [128] f32                               512
// A     : [3][64] f32                             768
static const size_t B_XT   = 0;
static const size_t B_TABF = 68157440ull;
static const size_t B_TABI = B_TABF + 2129920ull;
static const size_t B_WFR  = B_TABI + 2129920ull;
static const size_t B_ZFR  = B_WFR  + 131072ull;
static const size_t B_XPF  = B_ZFR  + 1048576ull;
static const size_t B_VP   = B_XPF  + 20971520ull;
static const size_t B_G    = B_VP   + 327680ull;
static const size_t B_A    = B_G    + 512ull;

// ---------------- trig tables in MFMA fragment order ----------------
__global__ void k_prep(_Float16* __restrict__ tabF, _Float16* __restrict__ tabI) {
    int idx = blockIdx.x * 256 + threadIdx.x;
    if (idx >= NPP * 64) return;
    int t = idx >> 6, k = idx & 63;
    float c = 0.f, s = 0.f;
    if (t < NP) {
        int m = (int)(((long long)t * (long long)k) % NP);
        float th = (float)m * (PI2 / (float)NP);
        sincosf(th, &s, &c);
    }
    float al = (k == 0) ? (1.f / NP) : (2.f / NP);
    {   // tabF: B[k=t][col=m]
        int gs = t >> 5, lh = (t >> 3) & 3, j = t & 7;
        int m0 = 2 * k, m1 = 2 * k + 1;
        tabF[(((size_t)gs * 8 + (m0 >> 4)) * 64 + (m0 & 15) + 16 * lh) * 8 + j] = (_Float16)c;
        tabF[(((size_t)gs * 8 + (m1 >> 4)) * 64 + (m1 & 15) + 16 * lh) * 8 + j] = (_Float16)s;
    }
    {   // tabI: B[k=m][col=t], alpha folded
        int tf = t >> 4, lt = t & 15;
        int m0 = 2 * k, m1 = 2 * k + 1;
        tabI[(((size_t)(m0 >> 5) * TFR + tf) * 64 + lt + 16 * ((m0 >> 3) & 3)) * 8 + (m0 & 7)] = (_Float16)(al * c);
        tabI[(((size_t)(m1 >> 5) * TFR + tf) * 64 + lt + 16 * ((m1 >> 3) & 3)) * 8 + (m1 & 7)] = (_Float16)(al * s);
    }
}

// ---------------- w_w hi/lo f16 in A-frag order ----------------
__global__ void k_prep_w(const float* __restrict__ ww, _Float16* __restrict__ Wfrag) {
    int idx = blockIdx.x * 256 + threadIdx.x;
    if (idx >= NL * DV * DV) return;
    int l = idx >> 12, cd = idx & 4095, c = cd >> 6, d = cd & 63;
    float wv = ww[((size_t)l * DV + c) * DV + d];     // A[row=d][k=c]
    _Float16 h = (_Float16)wv;
    _Float16 lo = (_Float16)(wv - (float)h);
    int ks = c >> 5, mf = d >> 4;
    int lane = (d & 15) + 16 * ((c >> 3) & 3), j = c & 7;
    Wfrag[((((size_t)l * 2 + 0) * 2 + ks) * 4 + mf) * 512 + (size_t)lane * 8 + j] = h;
    Wfrag[((((size_t)l * 2 + 1) * 2 + ks) * 4 + mf) * 512 + (size_t)lane * 8 + j] = lo;
}

// ---------------- rank-2 layer-0 local coefficients: A0/A1/A2[d] ----------------
__global__ void k_prep_p(const float* __restrict__ pw, const float* __restrict__ pb,
                         const float* __restrict__ ww, float* __restrict__ A) {
    int d = threadIdx.x;
    float a0 = 0.f, a1 = 0.f, a2 = 0.f;
    #pragma unroll 8
    for (int c = 0; c < DV; ++c) {
        float w = ww[(size_t)c * DV + d];   // layer 0
        a0 = fmaf(pw[c], w, a0);
        a1 = fmaf(pw[DV + c], w, a1);
        a2 = fmaf(pb[c], w, a2);
    }
    A[d] = a0; A[64 + d] = a1; A[128 + d] = a2;
}

// ---------------- G[m] = DFT(grid) ----------------
__global__ void k_gd(const float* __restrict__ grd, float* __restrict__ G) {
    __shared__ float rb[256];
    int m = blockIdx.x, k = m >> 1, comp = m & 1;
    int tid = threadIdx.x;
    float s = 0.f;
    for (int t = tid; t < NT; t += 256) {
        int mm = (int)(((long long)t * (long long)k) % NP);
        float th = (float)mm * (PI2 / (float)NP);
        float sn, cs; sincosf(th, &sn, &cs);
        s += grd[t] * (comp ? sn : cs);
    }
    rb[tid] = s; __syncthreads();
    for (int h = 128; h > 0; h >>= 1) { if (tid < h) rb[tid] += rb[tid + h]; __syncthreads(); }
    if (tid == 0) G[m] = rb[0];
}

// ---------------- partial DFT of v (A rows = batch) ----------------
__launch_bounds__(256)
__global__ void k_fdft_v(const float* __restrict__ v, const _Float16* __restrict__ tabF,
                         _Float16* __restrict__ Vp) {
    int ksb = blockIdx.x;
    int tid = threadIdx.x, w = tid >> 6, lane = tid & 63, g = lane >> 4, r = lane & 15;
    const half8* tFv = (const half8*)tabF;
    f32x4 acc[4][2];
    #pragma unroll
    for (int mf = 0; mf < 4; ++mf)
        #pragma unroll
        for (int nf = 0; nf < 2; ++nf) acc[mf][nf] = (f32x4){0.f, 0.f, 0.f, 0.f};
    for (int s = 0; s < SPB; ++s) {
        int gs = ksb * SPB + s;
        int t0 = gs * 32 + g * 8;
        half8 a[4];
        #pragma unroll
        for (int mf = 0; mf < 4; ++mf) {
            int brow = mf * 16 + r;
            half8 hv;
            if (t0 < NT) {
                const float4* pv = (const float4*)&v[(size_t)brow * NT + t0];
                float4 v0 = pv[0], v1 = pv[1];
                hv[0] = (_Float16)v0.x; hv[1] = (_Float16)v0.y; hv[2] = (_Float16)v0.z; hv[3] = (_Float16)v0.w;
                hv[4] = (_Float16)v1.x; hv[5] = (_Float16)v1.y; hv[6] = (_Float16)v1.z; hv[7] = (_Float16)v1.w;
            } else {
                #pragma unroll
                for (int j = 0; j < 8; ++j) hv[j] = (_Float16)0.f;
            }
            a[mf] = hv;
        }
        half8 bb[2];
        #pragma unroll
        for (int nf = 0; nf < 2; ++nf) bb[nf] = tFv[((size_t)gs * 8 + w * 2 + nf) * 64 + lane];
        #pragma unroll
        for (int mf = 0; mf < 4; ++mf)
            #pragma unroll
            for (int nf = 0; nf < 2; ++nf)
                acc[mf][nf] = __builtin_amdgcn_mfma_f32_16x16x32_f16(a[mf], bb[nf], acc[mf][nf], 0, 0, 0);
    }
    #pragma unroll
    for (int mf = 0; mf < 4; ++mf)
        #pragma unroll
        for (int nf = 0; nf < 2; ++nf)
            #pragma unroll
            for (int reg = 0; reg < 4; ++reg) {
                int brow = mf * 16 + g * 4 + reg;
                int m = w * 32 + nf * 16 + r;
                Vp[((size_t)ksb * NB + brow) * 128 + m] = (_Float16)acc[mf][nf][reg];
            }
}

// ---------------- standalone fwd DFT of xT: LDS-staged A, frag-order partials ----------------
__launch_bounds__(256)
__global__ void k_fdft(const _Float16* __restrict__ xT, const _Float16* __restrict__ tabF,
                       _Float16* __restrict__ xpf) {
    __shared__ _Float16 xls[2048];   // [64c][32t] swizzled, 4 KiB
    int sb = blockIdx.x, b = blockIdx.y;
    int tid = threadIdx.x, w = tid >> 6, lane = tid & 63, g = lane >> 4, r = lane & 15;
    const half8* tFv = (const half8*)tabF;
    f32x4 acc[4][2];
    #pragma unroll
    for (int cf = 0; cf < 4; ++cf)
        #pragma unroll
        for (int nf = 0; nf < 2; ++nf) acc[cf][nf] = (f32x4){0.f, 0.f, 0.f, 0.f};
    int tl = tid >> 3, c0 = (tid & 7) * 8;
    #pragma unroll 1
    for (int s = 0; s < SPB; ++s) {
        int gs = sb * SPB + s;
        half8 vv = *(const half8*)&xT[((size_t)b * NPP + gs * 32 + tl) * 64 + c0];
        __syncthreads();   // protect previous iteration's reads
        #pragma unroll
        for (int j = 0; j < 8; ++j) {
            int c = c0 + j;
            xls[c * 32 + (tl ^ (((c >> 3) & 3) << 3))] = vv[j];
        }
        __syncthreads();
        half8 a[4], bb[2];
        #pragma unroll
        for (int cf = 0; cf < 4; ++cf) {
            int c = cf * 16 + r;
            a[cf] = *(const half8*)&xls[c * 32 + ((g * 8) ^ ((((c >> 3) & 3)) << 3))];
        }
        #pragma unroll
        for (int nf = 0; nf < 2; ++nf) bb[nf] = tFv[((size_t)gs * 8 + w * 2 + nf) * 64 + lane];
        #pragma unroll
        for (int cf = 0; cf < 4; ++cf)
            #pragma unroll
            for (int nf = 0; nf < 2; ++nf)
                acc[cf][nf] = __builtin_amdgcn_mfma_f32_16x16x32_f16(a[cf], bb[nf], acc[cf][nf], 0, 0, 0);
    }
    _Float16* xp = xpf + (((size_t)sb * NB + b) * 4 + w) * 2048;
    #pragma unroll
    for (int cf = 0; cf < 4; ++cf)
        #pragma unroll
        for (int nf = 0; nf < 2; ++nf) {
            half4 h4;
            #pragma unroll
            for (int reg = 0; reg < 4; ++reg) h4[reg] = (_Float16)acc[cf][nf][reg];
            *(half4*)&xp[(cf * 2 + nf) * 256 + lane * 4] = h4;
        }
}

// ---------------- spectral mix layer 0 (rank-2 X build) ----------------
__launch_bounds__(256)
__global__ void k_spec0(const _Float16* __restrict__ Vp, const float* __restrict__ G,
                        const float* __restrict__ pw, const float* __restrict__ pb,
                        const float* __restrict__ fw_l, _Float16* __restrict__ zfr) {
    __shared__ float Xs[64][32];
    __shared__ float Vs[32], Gs[32];
    int b = blockIdx.y, kq = blockIdx.x, tid = threadIdx.x;
    if (tid < 32) {
        int m = kq * 32 + tid;
        float ssum = 0.f;
        #pragma unroll
        for (int ks = 0; ks < KSP; ++ks) ssum += (float)Vp[((size_t)ks * NB + b) * 128 + m];
        Vs[tid] = ssum;
        Gs[tid] = G[m];
    }
    __syncthreads();
    #pragma unroll
    for (int q = 0; q < 8; ++q) {
        int flat = q * 256 + tid;
        int i = flat >> 5, ml = flat & 31;
        float xv = pw[i] * Vs[ml] + pw[64 + i] * Gs[ml];
        if (kq == 0 && ml == 0) xv += pb[i] * (float)NT;
        Xs[i][ml] = xv;
    }
    __syncthreads();
    #pragma unroll
    for (int q = 0; q < 4; ++q) {
        int flat = q * 256 + tid;
        int o = flat >> 4, kl = flat & 15;
        int k = kq * 16 + kl;
        float yr = 0.f, yi = 0.f;
        #pragma unroll 8
        for (int i = 0; i < 64; ++i) {
            float2 xv = *(const float2*)&Xs[i][2 * kl];
            float2 wv = *(const float2*)&fw_l[(((size_t)i * DV + o) * 64 + k) * 2];
            yr = fmaf(xv.x, wv.x, fmaf(xv.y, wv.y, yr));
            yi = fmaf(xv.x, wv.y, fmaf(-xv.y, wv.x, yi));
        }
        int mf = o >> 4, mm = 2 * kl, m1 = mm + 1;
        zfr[((((size_t)b * 4 + kq) * 4 + mf) * 64 + (o & 15) + 16 * (mm >> 3)) * 8 + (mm & 7)] = (_Float16)yr;
        zfr[((((size_t)b * 4 + kq) * 4 + mf) * 64 + (o & 15) + 16 * (m1 >> 3)) * 8 + (m1 & 7)] = (_Float16)(-yi);
    }
}

// ---------------- spectral mix layers 1..3 (frag-ordered partial reduce) ----------------
__launch_bounds__(256)
__global__ void k_spec(const _Float16* __restrict__ xpf, const float* __restrict__ fw_l,
                       _Float16* __restrict__ zfr) {
    __shared__ float Xs[64][32];
    int b = blockIdx.y, kq = blockIdx.x, tid = threadIdx.x;
    float a8[8];
    #pragma unroll
    for (int e = 0; e < 8; ++e) a8[e] = 0.f;
    const half8* src = (const half8*)xpf;
    size_t base8 = ((size_t)b * 4 + kq) * 256 + tid;
    const size_t step8 = (size_t)NB * 4 * 256;
    for (int ks = 0; ks < KSP; ++ks) {
        half8 vv = src[base8 + (size_t)ks * step8];
        #pragma unroll
        for (int e = 0; e < 8; ++e) a8[e] += (float)vv[e];
    }
    int cf = tid >> 6, nf2 = (tid >> 5) & 1, lane0 = (tid & 31) * 2;
    #pragma unroll
    for (int e = 0; e < 8; ++e) {
        int lane = lane0 + (e >> 2), reg = e & 3;
        int g = lane >> 4, r = lane & 15;
        Xs[cf * 16 + g * 4 + reg][nf2 * 16 + r] = a8[e];
    }
    __syncthreads();
    #pragma unroll
    for (int q = 0; q < 4; ++q) {
        int flat = q * 256 + tid;
        int o = flat >> 4, kl = flat & 15;
        int k = kq * 16 + kl;
        float yr = 0.f, yi = 0.f;
        #pragma unroll 8
        for (int i = 0; i < 64; ++i) {
            float2 xv = *(const float2*)&Xs[i][2 * kl];
            float2 wv = *(const float2*)&fw_l[(((size_t)i * DV + o) * 64 + k) * 2];
            yr = fmaf(xv.x, wv.x, fmaf(xv.y, wv.y, yr));
            yi = fmaf(xv.x, wv.y, fmaf(-xv.y, wv.x, yi));
        }
        int mf = o >> 4, mm = 2 * kl, m1 = mm + 1;
        zfr[((((size_t)b * 4 + kq) * 4 + mf) * 64 + (o & 15) + 16 * (mm >> 3)) * 8 + (mm & 7)] = (_Float16)yr;
        zfr[((((size_t)b * 4 + kq) * 4 + mf) * 64 + (o & 15) + 16 * (m1 >> 3)) * 8 + (m1 & 7)] = (_Float16)(-yi);
    }
}

// ---------------- inverse DFT + local + bias (+relu | +q_w reduce), straight-line ----------------
// MODE: 0 = FIRST (rank-2 local from v/grid), 1 = MID, 2 = LAST
template <int MODE>
__launch_bounds__(256)
__global__ void k_inv(const _Float16* __restrict__ zfr, const _Float16* __restrict__ tabI,
                      const _Float16* __restrict__ Wl, const float* __restrict__ wb_l,
                      const float* __restrict__ qw, const float* __restrict__ qb,
                      const float* __restrict__ v, const float* __restrict__ grd,
                      const float* __restrict__ A,
                      _Float16* __restrict__ xT, float* __restrict__ out) {
    __shared__ _Float16 xlt[128 * 64];   // t-major swizzled, 16 KiB (non-LAST)
    __shared__ float red[4][2][64];      // LAST
    __shared__ float Asm[3][64];         // FIRST
    int b = blockIdx.y, ksb = blockIdx.x;
    int tid = threadIdx.x, w = tid >> 6, lane = tid & 63;
    int g = lane >> 4, r = lane & 15;
    int tw = ksb * 128 + w * 32;
    const half8* zfv = (const half8*)zfr;
    const half8* tIv = (const half8*)tabI;
    const half8* wfv = (const half8*)Wl;

    if (MODE == 0) {
        if (tid < 192) Asm[tid >> 6][tid & 63] = A[tid];
        __syncthreads();
    }

    f32x4 acc[4][2];
    #pragma unroll
    for (int mf = 0; mf < 4; ++mf)
        #pragma unroll
        for (int nf = 0; nf < 2; ++nf) acc[mf][nf] = (f32x4){0.f, 0.f, 0.f, 0.f};

    // ---- spectral: A=z, B=tabI ----
    #pragma unroll
    for (int ks4 = 0; ks4 < 4; ++ks4) {
        half8 az[4], bt[2];
        #pragma unroll
        for (int mf = 0; mf < 4; ++mf)
            az[mf] = zfv[(((size_t)b * 4 + ks4) * 4 + mf) * 64 + lane];
        #pragma unroll
        for (int nf = 0; nf < 2; ++nf)
            bt[nf] = tIv[((size_t)ks4 * TFR + (tw >> 4) + nf) * 64 + lane];
        #pragma unroll
        for (int mf = 0; mf < 4; ++mf)
            #pragma unroll
            for (int nf = 0; nf < 2; ++nf)
                acc[mf][nf] = __builtin_amdgcn_mfma_f32_16x16x32_f16(az[mf], bt[nf], acc[mf][nf], 0, 0, 0);
    }
    // ---- local: (Whi + Wlo) * x  (MID/LAST only) ----
    if (MODE != 0) {
        half8 xb[2][2];
        #pragma unroll
        for (int ks = 0; ks < 2; ++ks)
            #pragma unroll
            for (int nf = 0; nf < 2; ++nf)
                xb[ks][nf] = *(const half8*)&xT[((size_t)b * NPP + tw + nf * 16 + r) * 64 + ks * 32 + g * 8];
        #pragma unroll
        for (int hl = 0; hl < 2; ++hl)
            #pragma unroll
            for (int ks = 0; ks < 2; ++ks) {
                half8 aw[4];
                #pragma unroll
                for (int mf = 0; mf < 4; ++mf)
                    aw[mf] = wfv[((size_t)(hl * 2 + ks) * 4 + mf) * 64 + lane];
                #pragma unroll
                for (int mf = 0; mf < 4; ++mf)
                    #pragma unroll
                    for (int nf = 0; nf < 2; ++nf)
                        acc[mf][nf] = __builtin_amdgcn_mfma_f32_16x16x32_f16(aw[mf], xb[ks][nf], acc[mf][nf], 0, 0, 0);
            }
    }

    if (MODE != 2) {
        // FIRST: rank-2 local from v/grid in f32
        float vv[2], gg[2];
        if (MODE == 0) {
            #pragma unroll
            for (int nf = 0; nf < 2; ++nf) {
                int t = tw + nf * 16 + r;
                bool in = (t < NT);
                vv[nf] = in ? v[(size_t)b * NT + t] : 0.f;
                gg[nf] = in ? grd[t] : 0.f;
            }
        }
        // ---- epilogue: bias + relu -> swizzled t-major LDS -> coalesced xT store ----
        #pragma unroll
        for (int mf = 0; mf < 4; ++mf)
            #pragma unroll
            for (int nf = 0; nf < 2; ++nf) {
                int tl = w * 32 + nf * 16 + r;
                half4 h4;
                #pragma unroll
                for (int reg = 0; reg < 4; ++reg) {
                    int o = mf * 16 + g * 4 + reg;
                    float val = acc[mf][nf][reg] + wb_l[o];
                    if (MODE == 0)
                        val += fmaf(Asm[0][o], vv[nf], fmaf(Asm[1][o], gg[nf], Asm[2][o]));
                    h4[reg] = (_Float16)fmaxf(val, 0.f);
                }
                int idx = tl * 64 + ((mf * 16 + g * 4) ^ ((tl & 7) << 3));
                *(half4*)&xlt[idx] = h4;
            }
        __syncthreads();
        #pragma unroll
        for (int it = 0; it < 4; ++it) {
            int flat = it * 256 + tid;
            int t = flat >> 3, k = flat & 7;
            half8 vv8 = *(const half8*)&xlt[t * 64 + ((k * 8) ^ ((t & 7) << 3))];
            *(half8*)&xT[((size_t)b * NPP + ksb * 128 + t) * 64 + k * 8] = vv8;
        }
    } else {
        float p0 = 0.f, p1 = 0.f;
        #pragma unroll
        for (int mf = 0; mf < 4; ++mf)
            #pragma unroll
            for (int reg = 0; reg < 4; ++reg) {
                int o = mf * 16 + g * 4 + reg;
                float qq = qw[o], bias = wb_l[o];
                p0 = fmaf(acc[mf][0][reg] + bias, qq, p0);
                p1 = fmaf(acc[mf][1][reg] + bias, qq, p1);
            }
        red[w][0][lane] = p0;
        red[w][1][lane] = p1;
        __syncthreads();
        if (tid < 128) {
            int w2 = tid >> 5, nf2 = (tid >> 4) & 1, c2 = tid & 15;
            float s2 = 0.f;
            #pragma unroll
            for (int g2 = 0; g2 < 4; ++g2) s2 += red[w2][nf2][g2 * 16 + c2];
            int t = ksb * 128 + w2 * 32 + nf2 * 16 + c2;
            if (t < NT) out[(size_t)b * NT + t] = s2 + qb[0];
        }
    }
}

extern "C" void kernel_launch(void* const* d_in, const int* in_sizes, int n_in,
                              void* d_out, int out_size, void* d_ws, size_t ws_size,
                              hipStream_t stream) {
    const float* v   = (const float*)d_in[0];
    const float* grd = (const float*)d_in[1];
    const float* pw  = (const float*)d_in[2];
    const float* pb  = (const float*)d_in[3];
    const float* fw  = (const float*)d_in[4];
    const float* ww  = (const float*)d_in[5];
    const float* wb  = (const float*)d_in[6];
    const float* qw  = (const float*)d_in[7];
    const float* qb  = (const float*)d_in[8];
    float* out = (float*)d_out;

    char* wsb = (char*)d_ws;
    _Float16* xT    = (_Float16*)(wsb + B_XT);
    _Float16* tabFb = (_Float16*)(wsb + B_TABF);
    _Float16* tabIb = (_Float16*)(wsb + B_TABI);
    _Float16* Wfrag = (_Float16*)(wsb + B_WFR);
    _Float16* zfrag = (_Float16*)(wsb + B_ZFR);
    _Float16* xpf   = (_Float16*)(wsb + B_XPF);
    _Float16* Vpart = (_Float16*)(wsb + B_VP);
    float*    G     = (float*)(wsb + B_G);
    float*    A     = (float*)(wsb + B_A);

    k_prep<<<(NPP * 64 + 255) / 256, 256, 0, stream>>>(tabFb, tabIb);
    k_prep_w<<<(NL * DV * DV + 255) / 256, 256, 0, stream>>>(ww, Wfrag);
    k_prep_p<<<1, 64, 0, stream>>>(pw, pb, ww, A);
    k_gd<<<128, 256, 0, stream>>>(grd, G);
    k_fdft_v<<<KSP, 256, 0, stream>>>(v, tabFb, Vpart);

    for (int l = 0; l < NL; ++l) {
        if (l == 0) {
            k_spec0<<<dim3(4, NB), 256, 0, stream>>>(Vpart, G, pw, pb, fw, zfrag);
        } else {
            k_fdft<<<dim3(KSP, NB), 256, 0, stream>>>(xT, tabFb, xpf);
            k_spec<<<dim3(4, NB), 256, 0, stream>>>(xpf, fw + (size_t)l * DV * DV * 64 * 2, zfrag);
        }
        const _Float16* wf_l = Wfrag + (size_t)l * 8192;   // 2*2*4*64*8 per layer
        const float* wb_l = wb + (size_t)l * DV;
        if (l == 0)
            k_inv<0><<<dim3(NPP / 128, NB), 256, 0, stream>>>(
                zfrag, tabIb, wf_l, wb_l, qw, qb, v, grd, A, xT, out);
        else if (l < NL - 1)
            k_inv<1><<<dim3(NPP / 128, NB), 256, 0, stream>>>(
                zfrag, tabIb, wf_l, wb_l, qw, qb, v, grd, A, xT, out);
        else
            k_inv<2><<<dim3(NT / 128, NB), 256, 0, stream>>>(
                zfrag, tabIb, wf_l, wb_l, qw, qb, v, grd, A, xT, out);
    }
}

// Round 10
// 301.178 us; speedup vs baseline: 2.7446x; 1.0147x over previous
//
#include <hip/hip_runtime.h>

#define NT    8192
#define NP    8200
#define NPP   8320          // 65*128 = 260*32 = 520*16
#define NB    64
#define DV    64
#define NL    4
#define TFR   520
#define KSP   20            // t-splits for standalone fwd-DFT (20*13 = 260 steps)
#define SPB   13
#define PI2   6.28318530717958647692f

typedef _Float16 half8 __attribute__((ext_vector_type(8)));
typedef _Float16 half4 __attribute__((ext_vector_type(4)));
typedef float    f32x4 __attribute__((ext_vector_type(4)));

// ---------------- workspace layout (bytes) ----------------
static const size_t B_XT   = 0;
static const size_t B_TABF = 68157440ull;
static const size_t B_TABI = B_TABF + 2129920ull;
static const size_t B_WFR  = B_TABI + 2129920ull;
static const size_t B_ZFR  = B_WFR  + 131072ull;
static const size_t B_XPF  = B_ZFR  + 1048576ull;
static const size_t B_VP   = B_XPF  + 20971520ull;
static const size_t B_G    = B_VP   + 327680ull;
static const size_t B_A    = B_G    + 512ull;

// ---------------- trig tables in MFMA fragment order ----------------
__global__ void k_prep(_Float16* __restrict__ tabF, _Float16* __restrict__ tabI) {
    int idx = blockIdx.x * 256 + threadIdx.x;
    if (idx >= NPP * 64) return;
    int t = idx >> 6, k = idx & 63;
    float c = 0.f, s = 0.f;
    if (t < NP) {
        int m = (int)(((long long)t * (long long)k) % NP);
        float th = (float)m * (PI2 / (float)NP);
        sincosf(th, &s, &c);
    }
    float al = (k == 0) ? (1.f / NP) : (2.f / NP);
    {   // tabF: B[k=t][col=m]
        int gs = t >> 5, lh = (t >> 3) & 3, j = t & 7;
        int m0 = 2 * k, m1 = 2 * k + 1;
        tabF[(((size_t)gs * 8 + (m0 >> 4)) * 64 + (m0 & 15) + 16 * lh) * 8 + j] = (_Float16)c;
        tabF[(((size_t)gs * 8 + (m1 >> 4)) * 64 + (m1 & 15) + 16 * lh) * 8 + j] = (_Float16)s;
    }
    {   // tabI: B[k=m][col=t], alpha folded
        int tf = t >> 4, lt = t & 15;
        int m0 = 2 * k, m1 = 2 * k + 1;
        tabI[(((size_t)(m0 >> 5) * TFR + tf) * 64 + lt + 16 * ((m0 >> 3) & 3)) * 8 + (m0 & 7)] = (_Float16)(al * c);
        tabI[(((size_t)(m1 >> 5) * TFR + tf) * 64 + lt + 16 * ((m1 >> 3) & 3)) * 8 + (m1 & 7)] = (_Float16)(al * s);
    }
}

// ---------------- w_w hi/lo f16 in A-frag order ----------------
__global__ void k_prep_w(const float* __restrict__ ww, _Float16* __restrict__ Wfrag) {
    int idx = blockIdx.x * 256 + threadIdx.x;
    if (idx >= NL * DV * DV) return;
    int l = idx >> 12, cd = idx & 4095, c = cd >> 6, d = cd & 63;
    float wv = ww[((size_t)l * DV + c) * DV + d];     // A[row=d][k=c]
    _Float16 h = (_Float16)wv;
    _Float16 lo = (_Float16)(wv - (float)h);
    int ks = c >> 5, mf = d >> 4;
    int lane = (d & 15) + 16 * ((c >> 3) & 3), j = c & 7;
    Wfrag[((((size_t)l * 2 + 0) * 2 + ks) * 4 + mf) * 512 + (size_t)lane * 8 + j] = h;
    Wfrag[((((size_t)l * 2 + 1) * 2 + ks) * 4 + mf) * 512 + (size_t)lane * 8 + j] = lo;
}

// ---------------- rank-2 layer-0 local coefficients: A0/A1/A2[d] ----------------
__global__ void k_prep_p(const float* __restrict__ pw, const float* __restrict__ pb,
                         const float* __restrict__ ww, float* __restrict__ A) {
    int d = threadIdx.x;
    float a0 = 0.f, a1 = 0.f, a2 = 0.f;
    #pragma unroll 8
    for (int c = 0; c < DV; ++c) {
        float w = ww[(size_t)c * DV + d];   // layer 0
        a0 = fmaf(pw[c], w, a0);
        a1 = fmaf(pw[DV + c], w, a1);
        a2 = fmaf(pb[c], w, a2);
    }
    A[d] = a0; A[64 + d] = a1; A[128 + d] = a2;
}

// ---------------- G[m] = DFT(grid) ----------------
__global__ void k_gd(const float* __restrict__ grd, float* __restrict__ G) {
    __shared__ float rb[256];
    int m = blockIdx.x, k = m >> 1, comp = m & 1;
    int tid = threadIdx.x;
    float s = 0.f;
    for (int t = tid; t < NT; t += 256) {
        int mm = (int)(((long long)t * (long long)k) % NP);
        float th = (float)mm * (PI2 / (float)NP);
        float sn, cs; sincosf(th, &sn, &cs);
        s += grd[t] * (comp ? sn : cs);
    }
    rb[tid] = s; __syncthreads();
    for (int h = 128; h > 0; h >>= 1) { if (tid < h) rb[tid] += rb[tid + h]; __syncthreads(); }
    if (tid == 0) G[m] = rb[0];
}

// ---------------- partial DFT of v (A rows = batch) ----------------
__launch_bounds__(256)
__global__ void k_fdft_v(const float* __restrict__ v, const _Float16* __restrict__ tabF,
                         _Float16* __restrict__ Vp) {
    int ksb = blockIdx.x;
    int tid = threadIdx.x, w = tid >> 6, lane = tid & 63, g = lane >> 4, r = lane & 15;
    const half8* tFv = (const half8*)tabF;
    f32x4 acc[4][2];
    #pragma unroll
    for (int mf = 0; mf < 4; ++mf)
        #pragma unroll
        for (int nf = 0; nf < 2; ++nf) acc[mf][nf] = (f32x4){0.f, 0.f, 0.f, 0.f};
    for (int s = 0; s < SPB; ++s) {
        int gs = ksb * SPB + s;
        int t0 = gs * 32 + g * 8;
        half8 a[4];
        #pragma unroll
        for (int mf = 0; mf < 4; ++mf) {
            int brow = mf * 16 + r;
            half8 hv;
            if (t0 < NT) {
                const float4* pv = (const float4*)&v[(size_t)brow * NT + t0];
                float4 v0 = pv[0], v1 = pv[1];
                hv[0] = (_Float16)v0.x; hv[1] = (_Float16)v0.y; hv[2] = (_Float16)v0.z; hv[3] = (_Float16)v0.w;
                hv[4] = (_Float16)v1.x; hv[5] = (_Float16)v1.y; hv[6] = (_Float16)v1.z; hv[7] = (_Float16)v1.w;
            } else {
                #pragma unroll
                for (int j = 0; j < 8; ++j) hv[j] = (_Float16)0.f;
            }
            a[mf] = hv;
        }
        half8 bb[2];
        #pragma unroll
        for (int nf = 0; nf < 2; ++nf) bb[nf] = tFv[((size_t)gs * 8 + w * 2 + nf) * 64 + lane];
        #pragma unroll
        for (int mf = 0; mf < 4; ++mf)
            #pragma unroll
            for (int nf = 0; nf < 2; ++nf)
                acc[mf][nf] = __builtin_amdgcn_mfma_f32_16x16x32_f16(a[mf], bb[nf], acc[mf][nf], 0, 0, 0);
    }
    #pragma unroll
    for (int mf = 0; mf < 4; ++mf)
        #pragma unroll
        for (int nf = 0; nf < 2; ++nf)
            #pragma unroll
            for (int reg = 0; reg < 4; ++reg) {
                int brow = mf * 16 + g * 4 + reg;
                int m = w * 32 + nf * 16 + r;
                Vp[((size_t)ksb * NB + brow) * 128 + m] = (_Float16)acc[mf][nf][reg];
            }
}

// ---------------- standalone fwd DFT of xT: double-buffered LDS stage ----------------
__launch_bounds__(256)
__global__ void k_fdft(const _Float16* __restrict__ xT, const _Float16* __restrict__ tabF,
                       _Float16* __restrict__ xpf) {
    __shared__ _Float16 xls[2][2048];   // 2 x [64c][32t] swizzled, 8 KiB
    int sb = blockIdx.x, b = blockIdx.y;
    int tid = threadIdx.x, w = tid >> 6, lane = tid & 63, g = lane >> 4, r = lane & 15;
    const half8* tFv = (const half8*)tabF;
    f32x4 acc[4][2];
    #pragma unroll
    for (int cf = 0; cf < 4; ++cf)
        #pragma unroll
        for (int nf = 0; nf < 2; ++nf) acc[cf][nf] = (f32x4){0.f, 0.f, 0.f, 0.f};
    int tl = tid >> 3, c0 = (tid & 7) * 8;

    // prologue: stage step 0 into buf 0
    half8 vv = *(const half8*)&xT[((size_t)b * NPP + (sb * SPB) * 32 + tl) * 64 + c0];
    #pragma unroll
    for (int j = 0; j < 8; ++j) {
        int c = c0 + j;
        xls[0][c * 32 + (tl ^ (((c >> 3) & 3) << 3))] = vv[j];
    }
    int cur = 0;
    #pragma unroll 1
    for (int s = 0; s < SPB; ++s) {
        int gs = sb * SPB + s;
        half8 vvn;
        if (s + 1 < SPB)
            vvn = *(const half8*)&xT[((size_t)b * NPP + (gs + 1) * 32 + tl) * 64 + c0];
        __syncthreads();   // buf[cur] writes visible; prior reads of buf[cur^1] retired
        if (s + 1 < SPB) {
            #pragma unroll
            for (int j = 0; j < 8; ++j) {
                int c = c0 + j;
                xls[cur ^ 1][c * 32 + (tl ^ (((c >> 3) & 3) << 3))] = vvn[j];
            }
        }
        half8 a[4], bb[2];
        #pragma unroll
        for (int cf = 0; cf < 4; ++cf) {
            int c = cf * 16 + r;
            a[cf] = *(const half8*)&xls[cur][c * 32 + ((g * 8) ^ ((((c >> 3) & 3)) << 3))];
        }
        #pragma unroll
        for (int nf = 0; nf < 2; ++nf) bb[nf] = tFv[((size_t)gs * 8 + w * 2 + nf) * 64 + lane];
        #pragma unroll
        for (int cf = 0; cf < 4; ++cf)
            #pragma unroll
            for (int nf = 0; nf < 2; ++nf)
                acc[cf][nf] = __builtin_amdgcn_mfma_f32_16x16x32_f16(a[cf], bb[nf], acc[cf][nf], 0, 0, 0);
        cur ^= 1;
    }
    _Float16* xp = xpf + (((size_t)sb * NB + b) * 4 + w) * 2048;
    #pragma unroll
    for (int cf = 0; cf < 4; ++cf)
        #pragma unroll
        for (int nf = 0; nf < 2; ++nf) {
            half4 h4;
            #pragma unroll
            for (int reg = 0; reg < 4; ++reg) h4[reg] = (_Float16)acc[cf][nf][reg];
            *(half4*)&xp[(cf * 2 + nf) * 256 + lane * 4] = h4;
        }
}

// ---------------- spectral mix layer 0 (rank-2 X build) ----------------
__launch_bounds__(256)
__global__ void k_spec0(const _Float16* __restrict__ Vp, const float* __restrict__ G,
                        const float* __restrict__ pw, const float* __restrict__ pb,
                        const float* __restrict__ fw_l, _Float16* __restrict__ zfr) {
    __shared__ float Xs[64][32];
    __shared__ float Vs[32], Gs[32];
    int b = blockIdx.y, kq = blockIdx.x, tid = threadIdx.x;
    if (tid < 32) {
        int m = kq * 32 + tid;
        float ssum = 0.f;
        #pragma unroll
        for (int ks = 0; ks < KSP; ++ks) ssum += (float)Vp[((size_t)ks * NB + b) * 128 + m];
        Vs[tid] = ssum;
        Gs[tid] = G[m];
    }
    __syncthreads();
    #pragma unroll
    for (int q = 0; q < 8; ++q) {
        int flat = q * 256 + tid;
        int i = flat >> 5, ml = flat & 31;
        float xv = pw[i] * Vs[ml] + pw[64 + i] * Gs[ml];
        if (kq == 0 && ml == 0) xv += pb[i] * (float)NT;
        Xs[i][ml] = xv;
    }
    __syncthreads();
    #pragma unroll
    for (int q = 0; q < 4; ++q) {
        int flat = q * 256 + tid;
        int o = flat >> 4, kl = flat & 15;
        int k = kq * 16 + kl;
        float yr = 0.f, yi = 0.f;
        #pragma unroll 8
        for (int i = 0; i < 64; ++i) {
            float2 xv = *(const float2*)&Xs[i][2 * kl];
            float2 wv = *(const float2*)&fw_l[(((size_t)i * DV + o) * 64 + k) * 2];
            yr = fmaf(xv.x, wv.x, fmaf(xv.y, wv.y, yr));
            yi = fmaf(xv.x, wv.y, fmaf(-xv.y, wv.x, yi));
        }
        int mf = o >> 4, mm = 2 * kl, m1 = mm + 1;
        zfr[((((size_t)b * 4 + kq) * 4 + mf) * 64 + (o & 15) + 16 * (mm >> 3)) * 8 + (mm & 7)] = (_Float16)yr;
        zfr[((((size_t)b * 4 + kq) * 4 + mf) * 64 + (o & 15) + 16 * (m1 >> 3)) * 8 + (m1 & 7)] = (_Float16)(-yi);
    }
}

// ---------------- spectral mix layers 1..3 (frag-ordered partial reduce) ----------------
__launch_bounds__(256)
__global__ void k_spec(const _Float16* __restrict__ xpf, const float* __restrict__ fw_l,
                       _Float16* __restrict__ zfr) {
    __shared__ float Xs[64][32];
    int b = blockIdx.y, kq = blockIdx.x, tid = threadIdx.x;
    float a8[8];
    #pragma unroll
    for (int e = 0; e < 8; ++e) a8[e] = 0.f;
    const half8* src = (const half8*)xpf;
    size_t base8 = ((size_t)b * 4 + kq) * 256 + tid;
    const size_t step8 = (size_t)NB * 4 * 256;
    for (int ks = 0; ks < KSP; ++ks) {
        half8 vv = src[base8 + (size_t)ks * step8];
        #pragma unroll
        for (int e = 0; e < 8; ++e) a8[e] += (float)vv[e];
    }
    int cf = tid >> 6, nf2 = (tid >> 5) & 1, lane0 = (tid & 31) * 2;
    #pragma unroll
    for (int e = 0; e < 8; ++e) {
        int lane = lane0 + (e >> 2), reg = e & 3;
        int g = lane >> 4, r = lane & 15;
        Xs[cf * 16 + g * 4 + reg][nf2 * 16 + r] = a8[e];
    }
    __syncthreads();
    #pragma unroll
    for (int q = 0; q < 4; ++q) {
        int flat = q * 256 + tid;
        int o = flat >> 4, kl = flat & 15;
        int k = kq * 16 + kl;
        float yr = 0.f, yi = 0.f;
        #pragma unroll 8
        for (int i = 0; i < 64; ++i) {
            float2 xv = *(const float2*)&Xs[i][2 * kl];
            float2 wv = *(const float2*)&fw_l[(((size_t)i * DV + o) * 64 + k) * 2];
            yr = fmaf(xv.x, wv.x, fmaf(xv.y, wv.y, yr));
            yi = fmaf(xv.x, wv.y, fmaf(-xv.y, wv.x, yi));
        }
        int mf = o >> 4, mm = 2 * kl, m1 = mm + 1;
        zfr[((((size_t)b * 4 + kq) * 4 + mf) * 64 + (o & 15) + 16 * (mm >> 3)) * 8 + (mm & 7)] = (_Float16)yr;
        zfr[((((size_t)b * 4 + kq) * 4 + mf) * 64 + (o & 15) + 16 * (m1 >> 3)) * 8 + (m1 & 7)] = (_Float16)(-yi);
    }
}

// ---------------- inverse DFT + local + bias (+relu | +q_w reduce), barrier-free ----------------
// MODE: 0 = FIRST (rank-2 local from v/grid), 1 = MID, 2 = LAST
template <int MODE>
__launch_bounds__(256)
__global__ void k_inv(const _Float16* __restrict__ zfr, const _Float16* __restrict__ tabI,
                      const _Float16* __restrict__ Wl, const float* __restrict__ wb_l,
                      const float* __restrict__ qw, const float* __restrict__ qb,
                      const float* __restrict__ v, const float* __restrict__ grd,
                      const float* __restrict__ A,
                      _Float16* __restrict__ xT, float* __restrict__ out) {
    __shared__ _Float16 xw[4][2048];     // per-wave 4 KiB transpose tile (MODE 0/1)
    __shared__ float Asm[3][64];         // FIRST
    int b = blockIdx.y, ksb = blockIdx.x;
    int tid = threadIdx.x, w = tid >> 6, lane = tid & 63;
    int g = lane >> 4, r = lane & 15;
    int tw = ksb * 128 + w * 32;
    const half8* zfv = (const half8*)zfr;
    const half8* tIv = (const half8*)tabI;
    const half8* wfv = (const half8*)Wl;

    if (MODE == 0) {
        if (tid < 192) Asm[tid >> 6][tid & 63] = A[tid];
        __syncthreads();
    }

    f32x4 acc[4][2];
    #pragma unroll
    for (int mf = 0; mf < 4; ++mf)
        #pragma unroll
        for (int nf = 0; nf < 2; ++nf) acc[mf][nf] = (f32x4){0.f, 0.f, 0.f, 0.f};

    // ---- spectral: A=z, B=tabI ----
    #pragma unroll
    for (int ks4 = 0; ks4 < 4; ++ks4) {
        half8 az[4], bt[2];
        #pragma unroll
        for (int mf = 0; mf < 4; ++mf)
            az[mf] = zfv[(((size_t)b * 4 + ks4) * 4 + mf) * 64 + lane];
        #pragma unroll
        for (int nf = 0; nf < 2; ++nf)
            bt[nf] = tIv[((size_t)ks4 * TFR + (tw >> 4) + nf) * 64 + lane];
        #pragma unroll
        for (int mf = 0; mf < 4; ++mf)
            #pragma unroll
            for (int nf = 0; nf < 2; ++nf)
                acc[mf][nf] = __builtin_amdgcn_mfma_f32_16x16x32_f16(az[mf], bt[nf], acc[mf][nf], 0, 0, 0);
    }
    // ---- local: (Whi + Wlo) * x  (MID/LAST only) ----
    if (MODE != 0) {
        half8 xb[2][2];
        #pragma unroll
        for (int ks = 0; ks < 2; ++ks)
            #pragma unroll
            for (int nf = 0; nf < 2; ++nf)
                xb[ks][nf] = *(const half8*)&xT[((size_t)b * NPP + tw + nf * 16 + r) * 64 + ks * 32 + g * 8];
        #pragma unroll
        for (int hl = 0; hl < 2; ++hl)
            #pragma unroll
            for (int ks = 0; ks < 2; ++ks) {
                half8 aw[4];
                #pragma unroll
                for (int mf = 0; mf < 4; ++mf)
                    aw[mf] = wfv[((size_t)(hl * 2 + ks) * 4 + mf) * 64 + lane];
                #pragma unroll
                for (int mf = 0; mf < 4; ++mf)
                    #pragma unroll
                    for (int nf = 0; nf < 2; ++nf)
                        acc[mf][nf] = __builtin_amdgcn_mfma_f32_16x16x32_f16(aw[mf], xb[ks][nf], acc[mf][nf], 0, 0, 0);
            }
    }

    if (MODE != 2) {
        // FIRST: rank-2 local from v/grid in f32
        float vv[2], gg[2];
        if (MODE == 0) {
            #pragma unroll
            for (int nf = 0; nf < 2; ++nf) {
                int t = tw + nf * 16 + r;
                bool in = (t < NT);
                vv[nf] = in ? v[(size_t)b * NT + t] : 0.f;
                gg[nf] = in ? grd[t] : 0.f;
            }
        }
        // ---- wave-local epilogue: bias(+rank2)+relu -> swizzled LDS -> coalesced store ----
        #pragma unroll
        for (int mf = 0; mf < 4; ++mf)
            #pragma unroll
            for (int nf = 0; nf < 2; ++nf) {
                int tl = nf * 16 + r;            // t within wave's 32-slice
                half4 h4;
                #pragma unroll
                for (int reg = 0; reg < 4; ++reg) {
                    int o = mf * 16 + g * 4 + reg;
                    float val = acc[mf][nf][reg] + wb_l[o];
                    if (MODE == 0)
                        val += fmaf(Asm[0][o], vv[nf], fmaf(Asm[1][o], gg[nf], Asm[2][o]));
                    h4[reg] = (_Float16)fmaxf(val, 0.f);
                }
                int idx = tl * 64 + ((mf * 16 + g * 4) ^ ((tl & 7) << 3));
                *(half4*)&xw[w][idx] = h4;
            }
        // wave-local: ds writes->reads ordered by lgkmcnt, no barrier
        #pragma unroll
        for (int it = 0; it < 4; ++it) {
            int t = it * 8 + (lane >> 3);        // 0..31
            int cg = lane & 7;
            half8 vv8 = *(const half8*)&xw[w][t * 64 + ((cg * 8) ^ ((t & 7) << 3))];
            *(half8*)&xT[((size_t)b * NPP + tw + t) * 64 + cg * 8] = vv8;
        }
    } else {
        float p0 = 0.f, p1 = 0.f;
        #pragma unroll
        for (int mf = 0; mf < 4; ++mf)
            #pragma unroll
            for (int reg = 0; reg < 4; ++reg) {
                int o = mf * 16 + g * 4 + reg;
                float qq = qw[o], bias = wb_l[o];
                p0 = fmaf(acc[mf][0][reg] + bias, qq, p0);
                p1 = fmaf(acc[mf][1][reg] + bias, qq, p1);
            }
        // reduce over g (lane bits 4,5) via shuffles — barrier-free
        p0 += __shfl_xor(p0, 16); p0 += __shfl_xor(p0, 32);
        p1 += __shfl_xor(p1, 16); p1 += __shfl_xor(p1, 32);
        float qbv = qb[0];
        if (g == 0) out[(size_t)b * NT + tw + r]      = p0 + qbv;   // t always < NT (grid = NT/128)
        if (g == 1) out[(size_t)b * NT + tw + 16 + r] = p1 + qbv;
    }
}

extern "C" void kernel_launch(void* const* d_in, const int* in_sizes, int n_in,
                              void* d_out, int out_size, void* d_ws, size_t ws_size,
                              hipStream_t stream) {
    const float* v   = (const float*)d_in[0];
    const float* grd = (const float*)d_in[1];
    const float* pw  = (const float*)d_in[2];
    const float* pb  = (const float*)d_in[3];
    const float* fw  = (const float*)d_in[4];
    const float* ww  = (const float*)d_in[5];
    const float* wb  = (const float*)d_in[6];
    const float* qw  = (const float*)d_in[7];
    const float* qb  = (const float*)d_in[8];
    float* out = (float*)d_out;

    char* wsb = (char*)d_ws;
    _Float16* xT    = (_Float16*)(wsb + B_XT);
    _Float16* tabFb = (_Float16*)(wsb + B_TABF);
    _Float16* tabIb = (_Float16*)(wsb + B_TABI);
    _Float16* Wfrag = (_Float16*)(wsb + B_WFR);
    _Float16* zfrag = (_Float16*)(wsb + B_ZFR);
    _Float16* xpf   = (_Float16*)(wsb + B_XPF);
    _Float16* Vpart = (_Float16*)(wsb + B_VP);
    float*    G     = (float*)(wsb + B_G);
    float*    A     = (float*)(wsb + B_A);

    k_prep<<<(NPP * 64 + 255) / 256, 256, 0, stream>>>(tabFb, tabIb);
    k_prep_w<<<(NL * DV * DV + 255) / 256, 256, 0, stream>>>(ww, Wfrag);
    k_prep_p<<<1, 64, 0, stream>>>(pw, pb, ww, A);
    k_gd<<<128, 256, 0, stream>>>(grd, G);
    k_fdft_v<<<KSP, 256, 0, stream>>>(v, tabFb, Vpart);

    for (int l = 0; l < NL; ++l) {
        if (l == 0) {
            k_spec0<<<dim3(4, NB), 256, 0, stream>>>(Vpart, G, pw, pb, fw, zfrag);
        } else {
            k_fdft<<<dim3(KSP, NB), 256, 0, stream>>>(xT, tabFb, xpf);
            k_spec<<<dim3(4, NB), 256, 0, stream>>>(xpf, fw + (size_t)l * DV * DV * 64 * 2, zfrag);
        }
        const _Float16* wf_l = Wfrag + (size_t)l * 8192;   // 2*2*4*64*8 per layer
        const float* wb_l = wb + (size_t)l * DV;
        if (l == 0)
            k_inv<0><<<dim3(NPP / 128, NB), 256, 0, stream>>>(
                zfrag, tabIb, wf_l, wb_l, qw, qb, v, grd, A, xT, out);
        else if (l < NL - 1)
            k_inv<1><<<dim3(NPP / 128, NB), 256, 0, stream>>>(
                zfrag, tabIb, wf_l, wb_l, qw, qb, v, grd, A, xT, out);
        else
            k_inv<2><<<dim3(NT / 128, NB), 256, 0, stream>>>(
                zfrag, tabIb, wf_l, wb_l, qw, qb, v, grd, A, xT, out);
    }
}

// Round 11
// 297.220 us; speedup vs baseline: 2.7811x; 1.0133x over previous
//
#include <hip/hip_runtime.h>

#define NT    8192
#define NP    8200
#define NPP   8320          // 65*128 = 260*32 = 520*16
#define NB    64
#define DV    64
#define NL    4
#define TFR   520
#define KSP   20            // t-splits for standalone fwd-DFT (20*13 = 260 steps)
#define SPB   13
#define PI2   6.28318530717958647692f

typedef _Float16 half8 __attribute__((ext_vector_type(8)));
typedef _Float16 half4 __attribute__((ext_vector_type(4)));
typedef float    f32x4 __attribute__((ext_vector_type(4)));

// ---------------- workspace layout (bytes) ----------------
static const size_t B_XT   = 0;
static const size_t B_TABF = 68157440ull;
static const size_t B_TABI = B_TABF + 2129920ull;
static const size_t B_WFR  = B_TABI + 2129920ull;
static const size_t B_ZFR  = B_WFR  + 131072ull;
static const size_t B_XPF  = B_ZFR  + 1048576ull;
static const size_t B_VP   = B_XPF  + 20971520ull;
static const size_t B_G    = B_VP   + 327680ull;
static const size_t B_A    = B_G    + 512ull;

// ---------------- trig tables, output-major (one coalesced half8 per thread) ----------------
__global__ void k_prep(_Float16* __restrict__ tabF, _Float16* __restrict__ tabI) {
    int idx = blockIdx.x * 256 + threadIdx.x;
    if (idx < 133120) {                       // tabF: [260 gs][8 cf][64 lane][8 j]
        int lane = idx & 63;
        int rest = idx >> 6;                  // gs*8 + cf
        int cf = rest & 7, gs = rest >> 3;
        int ml = lane & 15, lh = lane >> 4;
        int m = cf * 16 + ml, k = m >> 1, comp = m & 1;
        half8 o;
        #pragma unroll
        for (int j = 0; j < 8; ++j) {
            int t = gs * 32 + lh * 8 + j;
            float val = 0.f;
            if (t < NP) {
                int mm = (int)(((long long)t * (long long)k) % NP);
                float th = (float)mm * (PI2 / (float)NP);
                float sn, cs; sincosf(th, &sn, &cs);
                val = comp ? sn : cs;
            }
            o[j] = (_Float16)val;
        }
        *(half8*)&tabF[(size_t)idx * 8] = o;
    } else if (idx < 266240) {                // tabI: [4 ks][520 tf][64 lane][8 j], alpha folded
        int id2 = idx - 133120;
        int lane = id2 & 63;
        int rest = id2 >> 6;                  // ks*520 + tf
        int tf = rest % 520, ks = rest / 520;
        int lt = lane & 15, mh = lane >> 4;
        int t = tf * 16 + lt;
        half8 o;
        #pragma unroll
        for (int j = 0; j < 8; ++j) {
            int m = ks * 32 + mh * 8 + j;
            int k = m >> 1, comp = m & 1;
            float val = 0.f;
            if (t < NP) {
                int mm = (int)(((long long)t * (long long)k) % NP);
                float th = (float)mm * (PI2 / (float)NP);
                float sn, cs; sincosf(th, &sn, &cs);
                float al = (k == 0) ? (1.f / NP) : (2.f / NP);
                val = al * (comp ? sn : cs);
            }
            o[j] = (_Float16)val;
        }
        *(half8*)&tabI[(size_t)id2 * 8] = o;
    }
}

// ---------------- w_w hi/lo f16 in A-frag order ----------------
__global__ void k_prep_w(const float* __restrict__ ww, _Float16* __restrict__ Wfrag) {
    int idx = blockIdx.x * 256 + threadIdx.x;
    if (idx >= NL * DV * DV) return;
    int l = idx >> 12, cd = idx & 4095, c = cd >> 6, d = cd & 63;
    float wv = ww[((size_t)l * DV + c) * DV + d];     // A[row=d][k=c]
    _Float16 h = (_Float16)wv;
    _Float16 lo = (_Float16)(wv - (float)h);
    int ks = c >> 5, mf = d >> 4;
    int lane = (d & 15) + 16 * ((c >> 3) & 3), j = c & 7;
    Wfrag[((((size_t)l * 2 + 0) * 2 + ks) * 4 + mf) * 512 + (size_t)lane * 8 + j] = h;
    Wfrag[((((size_t)l * 2 + 1) * 2 + ks) * 4 + mf) * 512 + (size_t)lane * 8 + j] = lo;
}

// ---------------- rank-2 layer-0 local coefficients: A0/A1/A2[d] ----------------
__global__ void k_prep_p(const float* __restrict__ pw, const float* __restrict__ pb,
                         const float* __restrict__ ww, float* __restrict__ A) {
    int d = threadIdx.x;
    float a0 = 0.f, a1 = 0.f, a2 = 0.f;
    #pragma unroll 8
    for (int c = 0; c < DV; ++c) {
        float w = ww[(size_t)c * DV + d];   // layer 0
        a0 = fmaf(pw[c], w, a0);
        a1 = fmaf(pw[DV + c], w, a1);
        a2 = fmaf(pb[c], w, a2);
    }
    A[d] = a0; A[64 + d] = a1; A[128 + d] = a2;
}

// ---------------- G[m] = DFT(grid) ----------------
__global__ void k_gd(const float* __restrict__ grd, float* __restrict__ G) {
    __shared__ float rb[256];
    int m = blockIdx.x, k = m >> 1, comp = m & 1;
    int tid = threadIdx.x;
    float s = 0.f;
    for (int t = tid; t < NT; t += 256) {
        int mm = (int)(((long long)t * (long long)k) % NP);
        float th = (float)mm * (PI2 / (float)NP);
        float sn, cs; sincosf(th, &sn, &cs);
        s += grd[t] * (comp ? sn : cs);
    }
    rb[tid] = s; __syncthreads();
    for (int h = 128; h > 0; h >>= 1) { if (tid < h) rb[tid] += rb[tid + h]; __syncthreads(); }
    if (tid == 0) G[m] = rb[0];
}

// ---------------- partial DFT of v (A rows = batch) ----------------
__launch_bounds__(256)
__global__ void k_fdft_v(const float* __restrict__ v, const _Float16* __restrict__ tabF,
                         _Float16* __restrict__ Vp) {
    int ksb = blockIdx.x;
    int tid = threadIdx.x, w = tid >> 6, lane = tid & 63, g = lane >> 4, r = lane & 15;
    const half8* tFv = (const half8*)tabF;
    f32x4 acc[4][2];
    #pragma unroll
    for (int mf = 0; mf < 4; ++mf)
        #pragma unroll
        for (int nf = 0; nf < 2; ++nf) acc[mf][nf] = (f32x4){0.f, 0.f, 0.f, 0.f};
    for (int s = 0; s < SPB; ++s) {
        int gs = ksb * SPB + s;
        int t0 = gs * 32 + g * 8;
        half8 a[4];
        #pragma unroll
        for (int mf = 0; mf < 4; ++mf) {
            int brow = mf * 16 + r;
            half8 hv;
            if (t0 < NT) {
                const float4* pv = (const float4*)&v[(size_t)brow * NT + t0];
                float4 v0 = pv[0], v1 = pv[1];
                hv[0] = (_Float16)v0.x; hv[1] = (_Float16)v0.y; hv[2] = (_Float16)v0.z; hv[3] = (_Float16)v0.w;
                hv[4] = (_Float16)v1.x; hv[5] = (_Float16)v1.y; hv[6] = (_Float16)v1.z; hv[7] = (_Float16)v1.w;
            } else {
                #pragma unroll
                for (int j = 0; j < 8; ++j) hv[j] = (_Float16)0.f;
            }
            a[mf] = hv;
        }
        half8 bb[2];
        #pragma unroll
        for (int nf = 0; nf < 2; ++nf) bb[nf] = tFv[((size_t)gs * 8 + w * 2 + nf) * 64 + lane];
        #pragma unroll
        for (int mf = 0; mf < 4; ++mf)
            #pragma unroll
            for (int nf = 0; nf < 2; ++nf)
                acc[mf][nf] = __builtin_amdgcn_mfma_f32_16x16x32_f16(a[mf], bb[nf], acc[mf][nf], 0, 0, 0);
    }
    #pragma unroll
    for (int mf = 0; mf < 4; ++mf)
        #pragma unroll
        for (int nf = 0; nf < 2; ++nf)
            #pragma unroll
            for (int reg = 0; reg < 4; ++reg) {
                int brow = mf * 16 + g * 4 + reg;
                int m = w * 32 + nf * 16 + r;
                Vp[((size_t)ksb * NB + brow) * 128 + m] = (_Float16)acc[mf][nf][reg];
            }
}

// ---------------- standalone fwd DFT of xT: double-buffered LDS stage ----------------
__launch_bounds__(256)
__global__ void k_fdft(const _Float16* __restrict__ xT, const _Float16* __restrict__ tabF,
                       _Float16* __restrict__ xpf) {
    __shared__ _Float16 xls[2][2048];   // 2 x [64c][32t] swizzled, 8 KiB
    int sb = blockIdx.x, b = blockIdx.y;
    int tid = threadIdx.x, w = tid >> 6, lane = tid & 63, g = lane >> 4, r = lane & 15;
    const half8* tFv = (const half8*)tabF;
    f32x4 acc[4][2];
    #pragma unroll
    for (int cf = 0; cf < 4; ++cf)
        #pragma unroll
        for (int nf = 0; nf < 2; ++nf) acc[cf][nf] = (f32x4){0.f, 0.f, 0.f, 0.f};
    int tl = tid >> 3, c0 = (tid & 7) * 8;

    half8 vv = *(const half8*)&xT[((size_t)b * NPP + (sb * SPB) * 32 + tl) * 64 + c0];
    #pragma unroll
    for (int j = 0; j < 8; ++j) {
        int c = c0 + j;
        xls[0][c * 32 + (tl ^ (((c >> 3) & 3) << 3))] = vv[j];
    }
    int cur = 0;
    #pragma unroll 1
    for (int s = 0; s < SPB; ++s) {
        int gs = sb * SPB + s;
        half8 vvn;
        if (s + 1 < SPB)
            vvn = *(const half8*)&xT[((size_t)b * NPP + (gs + 1) * 32 + tl) * 64 + c0];
        __syncthreads();
        if (s + 1 < SPB) {
            #pragma unroll
            for (int j = 0; j < 8; ++j) {
                int c = c0 + j;
                xls[cur ^ 1][c * 32 + (tl ^ (((c >> 3) & 3) << 3))] = vvn[j];
            }
        }
        half8 a[4], bb[2];
        #pragma unroll
        for (int cf = 0; cf < 4; ++cf) {
            int c = cf * 16 + r;
            a[cf] = *(const half8*)&xls[cur][c * 32 + ((g * 8) ^ ((((c >> 3) & 3)) << 3))];
        }
        #pragma unroll
        for (int nf = 0; nf < 2; ++nf) bb[nf] = tFv[((size_t)gs * 8 + w * 2 + nf) * 64 + lane];
        #pragma unroll
        for (int cf = 0; cf < 4; ++cf)
            #pragma unroll
            for (int nf = 0; nf < 2; ++nf)
                acc[cf][nf] = __builtin_amdgcn_mfma_f32_16x16x32_f16(a[cf], bb[nf], acc[cf][nf], 0, 0, 0);
        cur ^= 1;
    }
    _Float16* xp = xpf + (((size_t)sb * NB + b) * 4 + w) * 2048;
    #pragma unroll
    for (int cf = 0; cf < 4; ++cf)
        #pragma unroll
        for (int nf = 0; nf < 2; ++nf) {
            half4 h4;
            #pragma unroll
            for (int reg = 0; reg < 4; ++reg) h4[reg] = (_Float16)acc[cf][nf][reg];
            *(half4*)&xp[(cf * 2 + nf) * 256 + lane * 4] = h4;
        }
}

// ---------------- spectral mix layer 0 (rank-2 X build) ----------------
__launch_bounds__(256)
__global__ void k_spec0(const _Float16* __restrict__ Vp, const float* __restrict__ G,
                        const float* __restrict__ pw, const float* __restrict__ pb,
                        const float* __restrict__ fw_l, _Float16* __restrict__ zfr) {
    __shared__ float Xs[64][32];
    __shared__ float Vs[32], Gs[32];
    int b = blockIdx.y, kq = blockIdx.x, tid = threadIdx.x;
    if (tid < 32) {
        int m = kq * 32 + tid;
        float ssum = 0.f;
        #pragma unroll
        for (int ks = 0; ks < KSP; ++ks) ssum += (float)Vp[((size_t)ks * NB + b) * 128 + m];
        Vs[tid] = ssum;
        Gs[tid] = G[m];
    }
    __syncthreads();
    #pragma unroll
    for (int q = 0; q < 8; ++q) {
        int flat = q * 256 + tid;
        int i = flat >> 5, ml = flat & 31;
        float xv = pw[i] * Vs[ml] + pw[64 + i] * Gs[ml];
        if (kq == 0 && ml == 0) xv += pb[i] * (float)NT;
        Xs[i][ml] = xv;
    }
    __syncthreads();
    #pragma unroll
    for (int q = 0; q < 4; ++q) {
        int flat = q * 256 + tid;
        int o = flat >> 4, kl = flat & 15;
        int k = kq * 16 + kl;
        float yr = 0.f, yi = 0.f;
        #pragma unroll 8
        for (int i = 0; i < 64; ++i) {
            float2 xv = *(const float2*)&Xs[i][2 * kl];
            float2 wv = *(const float2*)&fw_l[(((size_t)i * DV + o) * 64 + k) * 2];
            yr = fmaf(xv.x, wv.x, fmaf(xv.y, wv.y, yr));
            yi = fmaf(xv.x, wv.y, fmaf(-xv.y, wv.x, yi));
        }
        int mf = o >> 4, mm = 2 * kl, m1 = mm + 1;
        zfr[((((size_t)b * 4 + kq) * 4 + mf) * 64 + (o & 15) + 16 * (mm >> 3)) * 8 + (mm & 7)] = (_Float16)yr;
        zfr[((((size_t)b * 4 + kq) * 4 + mf) * 64 + (o & 15) + 16 * (m1 >> 3)) * 8 + (m1 & 7)] = (_Float16)(-yi);
    }
}

// ---------------- spectral mix layers 1..3 (frag-ordered partial reduce) ----------------
__launch_bounds__(256)
__global__ void k_spec(const _Float16* __restrict__ xpf, const float* __restrict__ fw_l,
                       _Float16* __restrict__ zfr) {
    __shared__ float Xs[64][32];
    int b = blockIdx.y, kq = blockIdx.x, tid = threadIdx.x;
    float a8[8];
    #pragma unroll
    for (int e = 0; e < 8; ++e) a8[e] = 0.f;
    const half8* src = (const half8*)xpf;
    size_t base8 = ((size_t)b * 4 + kq) * 256 + tid;
    const size_t step8 = (size_t)NB * 4 * 256;
    for (int ks = 0; ks < KSP; ++ks) {
        half8 vv = src[base8 + (size_t)ks * step8];
        #pragma unroll
        for (int e = 0; e < 8; ++e) a8[e] += (float)vv[e];
    }
    int cf = tid >> 6, nf2 = (tid >> 5) & 1, lane0 = (tid & 31) * 2;
    #pragma unroll
    for (int e = 0; e < 8; ++e) {
        int lane = lane0 + (e >> 2), reg = e & 3;
        int g = lane >> 4, r = lane & 15;
        Xs[cf * 16 + g * 4 + reg][nf2 * 16 + r] = a8[e];
    }
    __syncthreads();
    #pragma unroll
    for (int q = 0; q < 4; ++q) {
        int flat = q * 256 + tid;
        int o = flat >> 4, kl = flat & 15;
        int k = kq * 16 + kl;
        float yr = 0.f, yi = 0.f;
        #pragma unroll 8
        for (int i = 0; i < 64; ++i) {
            float2 xv = *(const float2*)&Xs[i][2 * kl];
            float2 wv = *(const float2*)&fw_l[(((size_t)i * DV + o) * 64 + k) * 2];
            yr = fmaf(xv.x, wv.x, fmaf(xv.y, wv.y, yr));
            yi = fmaf(xv.x, wv.y, fmaf(-xv.y, wv.x, yi));
        }
        int mf = o >> 4, mm = 2 * kl, m1 = mm + 1;
        zfr[((((size_t)b * 4 + kq) * 4 + mf) * 64 + (o & 15) + 16 * (mm >> 3)) * 8 + (mm & 7)] = (_Float16)yr;
        zfr[((((size_t)b * 4 + kq) * 4 + mf) * 64 + (o & 15) + 16 * (m1 >> 3)) * 8 + (m1 & 7)] = (_Float16)(-yi);
    }
}

// ---------------- inverse DFT + local + bias (+relu | +q_w reduce), 1-wave blocks ----------------
// MODE: 0 = FIRST (rank-2 local from v/grid), 1 = MID, 2 = LAST
// grid (260, NB) for 0/1 (wid = ksb*4 + w), (256, NB) for 2.
template <int MODE>
__launch_bounds__(64)
__global__ void k_inv(const _Float16* __restrict__ zfr, const _Float16* __restrict__ tabI,
                      const _Float16* __restrict__ Wl, const float* __restrict__ wb_l,
                      const float* __restrict__ qw, const float* __restrict__ qb,
                      const float* __restrict__ v, const float* __restrict__ grd,
                      const float* __restrict__ A,
                      _Float16* __restrict__ xT, float* __restrict__ out) {
    __shared__ _Float16 xw[2048];        // 4 KiB wave-local transpose tile (MODE 0/1)
    __shared__ float Asm[3][64];         // FIRST
    int b = blockIdx.y;
    int wid = blockIdx.x;
    int ksb = wid >> 2, w = wid & 3;
    int lane = threadIdx.x;
    int g = lane >> 4, r = lane & 15;
    int tw = ksb * 128 + w * 32;
    const half8* zfv = (const half8*)zfr;
    const half8* tIv = (const half8*)tabI;
    const half8* wfv = (const half8*)Wl;

    if (MODE == 0) {
        // wave-local LDS fill; ordering by lgkmcnt, no barrier
        Asm[0][lane] = A[lane];
        Asm[1][lane] = A[64 + lane];
        Asm[2][lane] = A[128 + lane];
    }

    f32x4 acc[4][2];
    #pragma unroll
    for (int mf = 0; mf < 4; ++mf)
        #pragma unroll
        for (int nf = 0; nf < 2; ++nf) acc[mf][nf] = (f32x4){0.f, 0.f, 0.f, 0.f};

    // ---- spectral: A=z, B=tabI ----
    #pragma unroll
    for (int ks4 = 0; ks4 < 4; ++ks4) {
        half8 az[4], bt[2];
        #pragma unroll
        for (int mf = 0; mf < 4; ++mf)
            az[mf] = zfv[(((size_t)b * 4 + ks4) * 4 + mf) * 64 + lane];
        #pragma unroll
        for (int nf = 0; nf < 2; ++nf)
            bt[nf] = tIv[((size_t)ks4 * TFR + (tw >> 4) + nf) * 64 + lane];
        #pragma unroll
        for (int mf = 0; mf < 4; ++mf)
            #pragma unroll
            for (int nf = 0; nf < 2; ++nf)
                acc[mf][nf] = __builtin_amdgcn_mfma_f32_16x16x32_f16(az[mf], bt[nf], acc[mf][nf], 0, 0, 0);
    }
    // ---- local: (Whi + Wlo) * x  (MID/LAST only) ----
    if (MODE != 0) {
        half8 xb[2][2];
        #pragma unroll
        for (int ks = 0; ks < 2; ++ks)
            #pragma unroll
            for (int nf = 0; nf < 2; ++nf)
                xb[ks][nf] = *(const half8*)&xT[((size_t)b * NPP + tw + nf * 16 + r) * 64 + ks * 32 + g * 8];
        #pragma unroll
        for (int hl = 0; hl < 2; ++hl)
            #pragma unroll
            for (int ks = 0; ks < 2; ++ks) {
                half8 aw[4];
                #pragma unroll
                for (int mf = 0; mf < 4; ++mf)
                    aw[mf] = wfv[((size_t)(hl * 2 + ks) * 4 + mf) * 64 + lane];
                #pragma unroll
                for (int mf = 0; mf < 4; ++mf)
                    #pragma unroll
                    for (int nf = 0; nf < 2; ++nf)
                        acc[mf][nf] = __builtin_amdgcn_mfma_f32_16x16x32_f16(aw[mf], xb[ks][nf], acc[mf][nf], 0, 0, 0);
            }
    }

    if (MODE != 2) {
        float vv[2], gg[2];
        if (MODE == 0) {
            #pragma unroll
            for (int nf = 0; nf < 2; ++nf) {
                int t = tw + nf * 16 + r;
                bool in = (t < NT);
                vv[nf] = in ? v[(size_t)b * NT + t] : 0.f;
                gg[nf] = in ? grd[t] : 0.f;
            }
        }
        // ---- wave-local epilogue: bias(+rank2)+relu -> swizzled LDS -> coalesced store ----
        #pragma unroll
        for (int mf = 0; mf < 4; ++mf)
            #pragma unroll
            for (int nf = 0; nf < 2; ++nf) {
                int tl = nf * 16 + r;
                half4 h4;
                #pragma unroll
                for (int reg = 0; reg < 4; ++reg) {
                    int o = mf * 16 + g * 4 + reg;
                    float val = acc[mf][nf][reg] + wb_l[o];
                    if (MODE == 0)
                        val += fmaf(Asm[0][o], vv[nf], fmaf(Asm[1][o], gg[nf], Asm[2][o]));
                    h4[reg] = (_Float16)fmaxf(val, 0.f);
                }
                int idx = tl * 64 + ((mf * 16 + g * 4) ^ ((tl & 7) << 3));
                *(half4*)&xw[idx] = h4;
            }
        #pragma unroll
        for (int it = 0; it < 4; ++it) {
            int t = it * 8 + (lane >> 3);
            int cg = lane & 7;
            half8 vv8 = *(const half8*)&xw[t * 64 + ((cg * 8) ^ ((t & 7) << 3))];
            *(half8*)&xT[((size_t)b * NPP + tw + t) * 64 + cg * 8] = vv8;
        }
    } else {
        float p0 = 0.f, p1 = 0.f;
        #pragma unroll
        for (int mf = 0; mf < 4; ++mf)
            #pragma unroll
            for (int reg = 0; reg < 4; ++reg) {
                int o = mf * 16 + g * 4 + reg;
                float qq = qw[o], bias = wb_l[o];
                p0 = fmaf(acc[mf][0][reg] + bias, qq, p0);
                p1 = fmaf(acc[mf][1][reg] + bias, qq, p1);
            }
        p0 += __shfl_xor(p0, 16); p0 += __shfl_xor(p0, 32);
        p1 += __shfl_xor(p1, 16); p1 += __shfl_xor(p1, 32);
        float qbv = qb[0];
        if (g == 0) out[(size_t)b * NT + tw + r]      = p0 + qbv;
        if (g == 1) out[(size_t)b * NT + tw + 16 + r] = p1 + qbv;
    }
}

extern "C" void kernel_launch(void* const* d_in, const int* in_sizes, int n_in,
                              void* d_out, int out_size, void* d_ws, size_t ws_size,
                              hipStream_t stream) {
    const float* v   = (const float*)d_in[0];
    const float* grd = (const float*)d_in[1];
    const float* pw  = (const float*)d_in[2];
    const float* pb  = (const float*)d_in[3];
    const float* fw  = (const float*)d_in[4];
    const float* ww  = (const float*)d_in[5];
    const float* wb  = (const float*)d_in[6];
    const float* qw  = (const float*)d_in[7];
    const float* qb  = (const float*)d_in[8];
    float* out = (float*)d_out;

    char* wsb = (char*)d_ws;
    _Float16* xT    = (_Float16*)(wsb + B_XT);
    _Float16* tabFb = (_Float16*)(wsb + B_TABF);
    _Float16* tabIb = (_Float16*)(wsb + B_TABI);
    _Float16* Wfrag = (_Float16*)(wsb + B_WFR);
    _Float16* zfrag = (_Float16*)(wsb + B_ZFR);
    _Float16* xpf   = (_Float16*)(wsb + B_XPF);
    _Float16* Vpart = (_Float16*)(wsb + B_VP);
    float*    G     = (float*)(wsb + B_G);
    float*    A     = (float*)(wsb + B_A);

    k_prep<<<1040, 256, 0, stream>>>(tabFb, tabIb);
    k_prep_w<<<(NL * DV * DV + 255) / 256, 256, 0, stream>>>(ww, Wfrag);
    k_prep_p<<<1, 64, 0, stream>>>(pw, pb, ww, A);
    k_gd<<<128, 256, 0, stream>>>(grd, G);
    k_fdft_v<<<KSP, 256, 0, stream>>>(v, tabFb, Vpart);

    for (int l = 0; l < NL; ++l) {
        if (l == 0) {
            k_spec0<<<dim3(4, NB), 256, 0, stream>>>(Vpart, G, pw, pb, fw, zfrag);
        } else {
            k_fdft<<<dim3(KSP, NB), 256, 0, stream>>>(xT, tabFb, xpf);
            k_spec<<<dim3(4, NB), 256, 0, stream>>>(xpf, fw + (size_t)l * DV * DV * 64 * 2, zfrag);
        }
        const _Float16* wf_l = Wfrag + (size_t)l * 8192;   // 2*2*4*64*8 per layer
        const float* wb_l = wb + (size_t)l * DV;
        if (l == 0)
            k_inv<0><<<dim3(260, NB), 64, 0, stream>>>(
                zfrag, tabIb, wf_l, wb_l, qw, qb, v, grd, A, xT, out);
        else if (l < NL - 1)
            k_inv<1><<<dim3(260, NB), 64, 0, stream>>>(
                zfrag, tabIb, wf_l, wb_l, qw, qb, v, grd, A, xT, out);
        else
            k_inv<2><<<dim3(256, NB), 64, 0, stream>>>(
                zfrag, tabIb, wf_l, wb_l, qw, qb, v, grd, A, xT, out);
    }
}